// Round 1
// baseline (612.077 us; speedup 1.0000x reference)
//
#include <hip/hip_runtime.h>
#include <cfloat>
#include <math.h>

// Problem constants (fixed by the reference)
#define B_ROWS   4096
#define DIM      512
#define NPROTO   1000
#define NCLASSES 10000
#define KSEL     10
#define TM       16      // image rows per block in the prob GEMM

// ---------------------------------------------------------------------------
// Kernel 1: prob = img @ proto.T  (per 16-row tile, kept in LDS), then
// per-row top-10 indices via iterative wave argmax (lowest-index tie-break,
// matching jax.lax.top_k's selected set).
// ---------------------------------------------------------------------------
__global__ __launch_bounds__(512, 1) void k_prob_topk(
    const float* __restrict__ img, const float* __restrict__ proto,
    int* __restrict__ topk)
{
  __shared__ float simg[TM * DIM];       // 32 KB
  __shared__ float sprob[TM * NPROTO];   // 62.5 KB

  const int tid  = threadIdx.x;
  const int row0 = blockIdx.x * TM;

  // Stage image tile (16 x 512 f32, contiguous) as float4
  {
    const float4* src = reinterpret_cast<const float4*>(img + (size_t)row0 * DIM);
    float4* dst = reinterpret_cast<float4*>(simg);
#pragma unroll
    for (int i = 0; i < (TM * DIM / 4) / 512; ++i)
      dst[tid + i * 512] = src[tid + i * 512];
  }
  __syncthreads();

  // Thread blocking: wave id -> 2 rows (broadcast LDS reads within wave),
  // lane -> 4 consecutive protos. 4 chunks of 256 protos cover 1000.
  const int rowg = tid >> 6;          // 0..7
  const int pl   = tid & 63;
  const int r0 = rowg * 2, r1 = r0 + 1;
  const float* imA = simg + r0 * DIM;
  const float* imB = simg + r1 * DIM;

  for (int chunk = 0; chunk < 4; ++chunk) {
    const int pbase = chunk * 256 + pl * 4;
    float acc[2][4] = {{0.f,0.f,0.f,0.f},{0.f,0.f,0.f,0.f}};
    const float* pb[4];
#pragma unroll
    for (int j = 0; j < 4; ++j) {
      int p = pbase + j;
      pb[j] = proto + (size_t)(p < NPROTO ? p : 0) * DIM;
    }
#pragma unroll 1
    for (int db = 0; db < DIM; db += 16) {
      // hoist 16 d's of both image rows into registers (wave-uniform LDS reads)
      float4 a0[4], a1[4];
#pragma unroll
      for (int q = 0; q < 4; ++q) {
        a0[q] = *reinterpret_cast<const float4*>(imA + db + q * 4);
        a1[q] = *reinterpret_cast<const float4*>(imB + db + q * 4);
      }
#pragma unroll
      for (int j = 0; j < 4; ++j) {
        const float4* pr = reinterpret_cast<const float4*>(pb[j] + db);
#pragma unroll
        for (int q = 0; q < 4; ++q) {
          float4 b = pr[q];
          acc[0][j] = fmaf(a0[q].x, b.x, acc[0][j]);
          acc[0][j] = fmaf(a0[q].y, b.y, acc[0][j]);
          acc[0][j] = fmaf(a0[q].z, b.z, acc[0][j]);
          acc[0][j] = fmaf(a0[q].w, b.w, acc[0][j]);
          acc[1][j] = fmaf(a1[q].x, b.x, acc[1][j]);
          acc[1][j] = fmaf(a1[q].y, b.y, acc[1][j]);
          acc[1][j] = fmaf(a1[q].z, b.z, acc[1][j]);
          acc[1][j] = fmaf(a1[q].w, b.w, acc[1][j]);
        }
      }
    }
#pragma unroll
    for (int j = 0; j < 4; ++j) {
      int p = pbase + j;
      if (p < NPROTO) {
        sprob[r0 * NPROTO + p] = acc[0][j];
        sprob[r1 * NPROTO + p] = acc[1][j];
      }
    }
  }
  __syncthreads();

  // Top-10 per row: wave w handles rows 2w, 2w+1. Iterative argmax, then
  // knock the winner out with -FLT_MAX. Ties -> lowest index (jax semantics).
  const int wave = tid >> 6, lane = tid & 63;
  for (int rr = 0; rr < 2; ++rr) {
    const int r = wave * 2 + rr;
    float* vals = sprob + r * NPROTO;
    for (int kk = 0; kk < KSEL; ++kk) {
      float bv = -FLT_MAX;
      int   bi = 0x7fffffff;
      for (int j = lane; j < NPROTO; j += 64) {
        float v = vals[j];
        if (v > bv || (v == bv && j < bi)) { bv = v; bi = j; }
      }
#pragma unroll
      for (int off = 32; off; off >>= 1) {
        float ov = __shfl_down(bv, off);
        int   oi = __shfl_down(bi, off);
        if (ov > bv || (ov == bv && oi < bi)) { bv = ov; bi = oi; }
      }
      bi = __shfl(bi, 0);
      if (lane == 0) topk[(size_t)(row0 + r) * KSEL + kk] = bi;
      vals[bi] = -FLT_MAX;   // all lanes, same addr/value
      __syncthreads();       // uniform trip counts -> convergent; orders LDS
    }
  }
}

// ---------------------------------------------------------------------------
// Kernel 2: inverse L2 norm of each text row (one wave per row).
// ---------------------------------------------------------------------------
__global__ __launch_bounds__(256) void k_invnorm(
    const float* __restrict__ text, float* __restrict__ invn)
{
  const int gw   = (int)((blockIdx.x * 256 + threadIdx.x) >> 6);
  const int lane = threadIdx.x & 63;
  if (gw >= NCLASSES) return;
  const float4* t = reinterpret_cast<const float4*>(text + (size_t)gw * DIM);
  float s = 0.f;
#pragma unroll
  for (int i = 0; i < 2; ++i) {
    float4 v = t[lane + i * 64];
    s = fmaf(v.x, v.x, s); s = fmaf(v.y, v.y, s);
    s = fmaf(v.z, v.z, s); s = fmaf(v.w, v.w, s);
  }
#pragma unroll
  for (int off = 32; off; off >>= 1) s += __shfl_down(s, off);
  if (lane == 0) invn[gw] = 1.0f / sqrtf(s);
}

// ---------------------------------------------------------------------------
// Kernel 3: per image row -- zero the 10000-wide output row, then compute the
// 100 surviving logits (one wave per class, shuffle-reduced 512-dot).
// ---------------------------------------------------------------------------
__global__ __launch_bounds__(256) void k_fill(
    const float* __restrict__ img, const float* __restrict__ text,
    const int* __restrict__ topk, const float* __restrict__ invn,
    const float* __restrict__ logit_scale, float* __restrict__ out)
{
  __shared__ float simg[DIM];
  __shared__ int   sp[KSEL];

  const int row = blockIdx.x;
  const int tid = threadIdx.x;
  float* orow = out + (size_t)row * NCLASSES;

  // zero the row (2500 float4)
  {
    float4 z = {0.f, 0.f, 0.f, 0.f};
    float4* o4 = reinterpret_cast<float4*>(orow);
    for (int i = tid; i < NCLASSES / 4; i += 256) o4[i] = z;
  }
  if (tid < DIM / 4)
    reinterpret_cast<float4*>(simg)[tid] =
        reinterpret_cast<const float4*>(img + (size_t)row * DIM)[tid];
  if (tid < KSEL) sp[tid] = topk[(size_t)row * KSEL + tid];
  __syncthreads();   // drains the zero-stores (vmcnt(0)) before overwrites

  const float scale = expf(logit_scale[0]);
  const int wave = tid >> 6, lane = tid & 63;

  for (int i = 0; i < 25; ++i) {
    const int s = i * 4 + wave;               // 0..99
    const int c = sp[s / 10] * 10 + (s % 10); // class index
    const float4* t4 = reinterpret_cast<const float4*>(text + (size_t)c * DIM);
    const float4* a4 = reinterpret_cast<const float4*>(simg);
    float acc = 0.f;
#pragma unroll
    for (int q = 0; q < 2; ++q) {
      float4 b = t4[lane + q * 64];
      float4 a = a4[lane + q * 64];
      acc = fmaf(a.x, b.x, acc); acc = fmaf(a.y, b.y, acc);
      acc = fmaf(a.z, b.z, acc); acc = fmaf(a.w, b.w, acc);
    }
#pragma unroll
    for (int off = 32; off; off >>= 1) acc += __shfl_down(acc, off);
    if (lane == 0) orow[c] = acc * invn[c] * scale;
  }
}

// ---------------------------------------------------------------------------
extern "C" void kernel_launch(void* const* d_in, const int* in_sizes, int n_in,
                              void* d_out, int out_size, void* d_ws, size_t ws_size,
                              hipStream_t stream) {
  const float* img    = (const float*)d_in[0];
  const float* proto  = (const float*)d_in[1];
  const float* text   = (const float*)d_in[2];
  const float* lscale = (const float*)d_in[3];
  // d_in[4] = num_test (10) -- compile-time constant KSEL here.

  int*   topk = (int*)d_ws;
  float* invn = (float*)((char*)d_ws + (size_t)B_ROWS * KSEL * sizeof(int));
  float* out  = (float*)d_out;

  k_prob_topk<<<B_ROWS / TM, 512, 0, stream>>>(img, proto, topk);
  k_invnorm<<<(NCLASSES + 3) / 4, 256, 0, stream>>>(text, invn);
  k_fill<<<B_ROWS, 256, 0, stream>>>(img, text, topk, invn, lscale, out);
}

// Round 2
// 205.579 us; speedup vs baseline: 2.9773x; 2.9773x over previous
//
#include <hip/hip_runtime.h>
#include <cfloat>
#include <math.h>

// Problem constants (fixed by the reference)
#define B_ROWS   4096
#define DIM      512
#define NPROTO   1000
#define NCLASSES 10000
#define KSEL     10

// GEMM tiling
#define BM 64
#define BN 128
#define BK 16
#define PROB_LD 1024   // padded leading dim of prob scratch

// ---------------------------------------------------------------------------
// Kernel 1: prob = img @ proto.T  -- register-blocked f32 GEMM.
// Block computes 64 rows x 128 protos; 256 threads, 4x8 per thread.
// Double-buffered LDS (reg-staged). prob written to d_out scratch (stride 1024).
// ---------------------------------------------------------------------------
__global__ __launch_bounds__(256) void k_gemm(
    const float* __restrict__ img, const float* __restrict__ proto,
    float* __restrict__ prob)
{
  __shared__ float sA[2][BK][BM];   // 2 x 4 KB, k-major
  __shared__ float sB[2][BK][BN];   // 2 x 8 KB, k-major

  const int tid  = threadIdx.x;
  const int row0 = blockIdx.x * BM;
  const int col0 = blockIdx.y * BN;

  // staging mapping: thread -> (row ar, 4 dims at ac)
  const int ar = tid >> 2;          // 0..63
  const int ac = (tid & 3) * 4;     // 0,4,8,12
  // compute mapping: thread -> 4 rows (tm*4..), 8 cols (tn*4.., 64+tn*4..)
  const int tm = tid >> 4;          // 0..15
  const int tn = tid & 15;          // 0..15

  int pa = col0 + ar;      if (pa > NPROTO - 1) pa = NPROTO - 1;
  int pb = col0 + 64 + ar; if (pb > NPROTO - 1) pb = NPROTO - 1;
  const float* gA  = img   + (size_t)(row0 + ar) * DIM + ac;
  const float* gB0 = proto + (size_t)pa * DIM + ac;
  const float* gB1 = proto + (size_t)pb * DIM + ac;

  float4 ra, rb0, rb1;
  ra  = *(const float4*)(gA);
  rb0 = *(const float4*)(gB0);
  rb1 = *(const float4*)(gB1);

  // store tile 0 -> buf 0
  {
    sA[0][ac + 0][ar] = ra.x;  sA[0][ac + 1][ar] = ra.y;
    sA[0][ac + 2][ar] = ra.z;  sA[0][ac + 3][ar] = ra.w;
    sB[0][ac + 0][ar] = rb0.x; sB[0][ac + 1][ar] = rb0.y;
    sB[0][ac + 2][ar] = rb0.z; sB[0][ac + 3][ar] = rb0.w;
    sB[0][ac + 0][64 + ar] = rb1.x; sB[0][ac + 1][64 + ar] = rb1.y;
    sB[0][ac + 2][64 + ar] = rb1.z; sB[0][ac + 3][64 + ar] = rb1.w;
  }
  __syncthreads();

  float4 acc[4][2];
#pragma unroll
  for (int i = 0; i < 4; ++i) {
    acc[i][0] = make_float4(0.f, 0.f, 0.f, 0.f);
    acc[i][1] = make_float4(0.f, 0.f, 0.f, 0.f);
  }

  const int NKT = DIM / BK;   // 32
  for (int kt = 0; kt < NKT; ++kt) {
    const int cur = kt & 1, nxt = cur ^ 1;
    if (kt + 1 < NKT) {
      const int k0 = (kt + 1) * BK;
      ra  = *(const float4*)(gA + k0);
      rb0 = *(const float4*)(gB0 + k0);
      rb1 = *(const float4*)(gB1 + k0);
    }
#pragma unroll
    for (int kk = 0; kk < BK; ++kk) {
      float4 av  = *(const float4*)&sA[cur][kk][tm * 4];
      float4 bv0 = *(const float4*)&sB[cur][kk][tn * 4];
      float4 bv1 = *(const float4*)&sB[cur][kk][64 + tn * 4];
      float a;
#pragma unroll
      for (int i = 0; i < 4; ++i) {
        a = (i == 0) ? av.x : (i == 1) ? av.y : (i == 2) ? av.z : av.w;
        acc[i][0].x = fmaf(a, bv0.x, acc[i][0].x);
        acc[i][0].y = fmaf(a, bv0.y, acc[i][0].y);
        acc[i][0].z = fmaf(a, bv0.z, acc[i][0].z);
        acc[i][0].w = fmaf(a, bv0.w, acc[i][0].w);
        acc[i][1].x = fmaf(a, bv1.x, acc[i][1].x);
        acc[i][1].y = fmaf(a, bv1.y, acc[i][1].y);
        acc[i][1].z = fmaf(a, bv1.z, acc[i][1].z);
        acc[i][1].w = fmaf(a, bv1.w, acc[i][1].w);
      }
    }
    if (kt + 1 < NKT) {
      __syncthreads();   // all waves done reading buf[nxt] (iter kt-1)
      sA[nxt][ac + 0][ar] = ra.x;  sA[nxt][ac + 1][ar] = ra.y;
      sA[nxt][ac + 2][ar] = ra.z;  sA[nxt][ac + 3][ar] = ra.w;
      sB[nxt][ac + 0][ar] = rb0.x; sB[nxt][ac + 1][ar] = rb0.y;
      sB[nxt][ac + 2][ar] = rb0.z; sB[nxt][ac + 3][ar] = rb0.w;
      sB[nxt][ac + 0][64 + ar] = rb1.x; sB[nxt][ac + 1][64 + ar] = rb1.y;
      sB[nxt][ac + 2][64 + ar] = rb1.z; sB[nxt][ac + 3][64 + ar] = rb1.w;
      __syncthreads();   // stores visible before next compute
    }
  }

  // epilogue: prob[row][col], stride PROB_LD
#pragma unroll
  for (int i = 0; i < 4; ++i) {
    float* o = prob + (size_t)(row0 + tm * 4 + i) * PROB_LD + col0;
    *(float4*)(o + tn * 4)      = acc[i][0];
    *(float4*)(o + 64 + tn * 4) = acc[i][1];
  }
}

// ---------------------------------------------------------------------------
// Kernel 2: per-row top-10 (one wave per row; row cached in LDS).
// Lowest-index tie-break to match jax.lax.top_k's selected set.
// ---------------------------------------------------------------------------
__global__ __launch_bounds__(256) void k_topk(
    const float* __restrict__ prob, int* __restrict__ topk)
{
  __shared__ float srow[4][PROB_LD];   // 16 KB
  const int tid  = threadIdx.x;
  const int wave = tid >> 6, lane = tid & 63;
  const int row  = blockIdx.x * 4 + wave;

  const float* p = prob + (size_t)row * PROB_LD;
#pragma unroll
  for (int i = 0; i < PROB_LD / 64; ++i) {
    const int j = lane + i * 64;
    srow[wave][j] = (j < NPROTO) ? p[j] : -FLT_MAX;
  }
  // wave-private LDS; same-thread RAW ordering handled by compiler waits

  for (int kk = 0; kk < KSEL; ++kk) {
    float bv = -FLT_MAX;
    int   bi = 0x7fffffff;
#pragma unroll
    for (int i = 0; i < PROB_LD / 64; ++i) {
      const int j = lane + i * 64;
      float v = srow[wave][j];
      if (v > bv || (v == bv && j < bi)) { bv = v; bi = j; }
    }
#pragma unroll
    for (int off = 32; off; off >>= 1) {
      float ov = __shfl_down(bv, off);
      int   oi = __shfl_down(bi, off);
      if (ov > bv || (ov == bv && oi < bi)) { bv = ov; bi = oi; }
    }
    bi = __shfl(bi, 0);
    if (lane == 0) topk[(size_t)row * KSEL + kk] = bi;
    srow[wave][bi] = -FLT_MAX;   // all lanes, same addr/value
  }
}

// ---------------------------------------------------------------------------
// Kernel 3: inverse L2 norm of each text row (one wave per row).
// ---------------------------------------------------------------------------
__global__ __launch_bounds__(256) void k_invnorm(
    const float* __restrict__ text, float* __restrict__ invn)
{
  const int gw   = (int)((blockIdx.x * 256 + threadIdx.x) >> 6);
  const int lane = threadIdx.x & 63;
  if (gw >= NCLASSES) return;
  const float4* t = reinterpret_cast<const float4*>(text + (size_t)gw * DIM);
  float s = 0.f;
#pragma unroll
  for (int i = 0; i < 2; ++i) {
    float4 v = t[lane + i * 64];
    s = fmaf(v.x, v.x, s); s = fmaf(v.y, v.y, s);
    s = fmaf(v.z, v.z, s); s = fmaf(v.w, v.w, s);
  }
#pragma unroll
  for (int off = 32; off; off >>= 1) s += __shfl_down(s, off);
  if (lane == 0) invn[gw] = 1.0f / sqrtf(s);
}

// ---------------------------------------------------------------------------
// Kernel 4: per image row -- zero the 10000-wide output row, then compute the
// 100 surviving logits (one wave per class, shuffle-reduced 512-dot).
// ---------------------------------------------------------------------------
__global__ __launch_bounds__(256) void k_fill(
    const float* __restrict__ img, const float* __restrict__ text,
    const int* __restrict__ topk, const float* __restrict__ invn,
    const float* __restrict__ logit_scale, float* __restrict__ out)
{
  __shared__ float simg[DIM];
  __shared__ int   sp[KSEL];

  const int row = blockIdx.x;
  const int tid = threadIdx.x;
  float* orow = out + (size_t)row * NCLASSES;

  // zero the row (2500 float4)
  {
    float4 z = {0.f, 0.f, 0.f, 0.f};
    float4* o4 = reinterpret_cast<float4*>(orow);
    for (int i = tid; i < NCLASSES / 4; i += 256) o4[i] = z;
  }
  if (tid < DIM / 4)
    reinterpret_cast<float4*>(simg)[tid] =
        reinterpret_cast<const float4*>(img + (size_t)row * DIM)[tid];
  if (tid < KSEL) sp[tid] = topk[(size_t)row * KSEL + tid];
  __syncthreads();

  const float scale = expf(logit_scale[0]);
  const int wave = tid >> 6, lane = tid & 63;

  for (int i = 0; i < 25; ++i) {
    const int s = i * 4 + wave;               // 0..99
    const int c = sp[s / 10] * 10 + (s % 10); // class index
    const float4* t4 = reinterpret_cast<const float4*>(text + (size_t)c * DIM);
    const float4* a4 = reinterpret_cast<const float4*>(simg);
    float acc = 0.f;
#pragma unroll
    for (int q = 0; q < 2; ++q) {
      float4 b = t4[lane + q * 64];
      float4 a = a4[lane + q * 64];
      acc = fmaf(a.x, b.x, acc); acc = fmaf(a.y, b.y, acc);
      acc = fmaf(a.z, b.z, acc); acc = fmaf(a.w, b.w, acc);
    }
#pragma unroll
    for (int off = 32; off; off >>= 1) acc += __shfl_down(acc, off);
    if (lane == 0) orow[c] = acc * invn[c] * scale;
  }
}

// ---------------------------------------------------------------------------
extern "C" void kernel_launch(void* const* d_in, const int* in_sizes, int n_in,
                              void* d_out, int out_size, void* d_ws, size_t ws_size,
                              hipStream_t stream) {
  const float* img    = (const float*)d_in[0];
  const float* proto  = (const float*)d_in[1];
  const float* text   = (const float*)d_in[2];
  const float* lscale = (const float*)d_in[3];

  // prob scratch lives INSIDE d_out (16.8 MB of 163.8 MB); k_fill fully
  // overwrites d_out afterwards (same stream -> ordered).
  float* prob = (float*)d_out;
  int*   topk = (int*)d_ws;
  float* invn = (float*)((char*)d_ws + (size_t)B_ROWS * KSEL * sizeof(int));
  float* out  = (float*)d_out;

  k_gemm<<<dim3(B_ROWS / BM, (NPROTO + BN - 1) / BN), 256, 0, stream>>>(img, proto, prob);
  k_topk<<<B_ROWS / 4, 256, 0, stream>>>(prob, topk);
  k_invnorm<<<(NCLASSES + 3) / 4, 256, 0, stream>>>(text, invn);
  k_fill<<<B_ROWS, 256, 0, stream>>>(img, text, topk, invn, lscale, out);
}

// Round 3
// 161.429 us; speedup vs baseline: 3.7916x; 1.2735x over previous
//
#include <hip/hip_runtime.h>
#include <cfloat>
#include <math.h>

// Problem constants (fixed by the reference)
#define B_ROWS   4096
#define DIM      512
#define NPROTO   1000
#define NCLASSES 10000
#define KSEL     10
#define NPAIRS   (B_ROWS * KSEL)   // 40960 (row,proto) pairs
#define CAP      256               // bucket capacity (avg 41, Poisson -> <=90)

// GEMM tiling
#define BM 64
#define BN 128
#define BK 16
#define PROB_LD 1024   // padded leading dim of prob scratch

// ---------------------------------------------------------------------------
// Kernel 1: prob = img @ proto.T  -- register-blocked f32 GEMM (unchanged).
// ---------------------------------------------------------------------------
__global__ __launch_bounds__(256) void k_gemm(
    const float* __restrict__ img, const float* __restrict__ proto,
    float* __restrict__ prob)
{
  __shared__ float sA[2][BK][BM];
  __shared__ float sB[2][BK][BN];

  const int tid  = threadIdx.x;
  const int row0 = blockIdx.x * BM;
  const int col0 = blockIdx.y * BN;

  const int ar = tid >> 2;
  const int ac = (tid & 3) * 4;
  const int tm = tid >> 4;
  const int tn = tid & 15;

  int pa = col0 + ar;      if (pa > NPROTO - 1) pa = NPROTO - 1;
  int pb = col0 + 64 + ar; if (pb > NPROTO - 1) pb = NPROTO - 1;
  const float* gA  = img   + (size_t)(row0 + ar) * DIM + ac;
  const float* gB0 = proto + (size_t)pa * DIM + ac;
  const float* gB1 = proto + (size_t)pb * DIM + ac;

  float4 ra, rb0, rb1;
  ra  = *(const float4*)(gA);
  rb0 = *(const float4*)(gB0);
  rb1 = *(const float4*)(gB1);

  sA[0][ac + 0][ar] = ra.x;  sA[0][ac + 1][ar] = ra.y;
  sA[0][ac + 2][ar] = ra.z;  sA[0][ac + 3][ar] = ra.w;
  sB[0][ac + 0][ar] = rb0.x; sB[0][ac + 1][ar] = rb0.y;
  sB[0][ac + 2][ar] = rb0.z; sB[0][ac + 3][ar] = rb0.w;
  sB[0][ac + 0][64 + ar] = rb1.x; sB[0][ac + 1][64 + ar] = rb1.y;
  sB[0][ac + 2][64 + ar] = rb1.z; sB[0][ac + 3][64 + ar] = rb1.w;
  __syncthreads();

  float4 acc[4][2];
#pragma unroll
  for (int i = 0; i < 4; ++i) {
    acc[i][0] = make_float4(0.f, 0.f, 0.f, 0.f);
    acc[i][1] = make_float4(0.f, 0.f, 0.f, 0.f);
  }

  const int NKT = DIM / BK;
  for (int kt = 0; kt < NKT; ++kt) {
    const int cur = kt & 1, nxt = cur ^ 1;
    if (kt + 1 < NKT) {
      const int k0 = (kt + 1) * BK;
      ra  = *(const float4*)(gA + k0);
      rb0 = *(const float4*)(gB0 + k0);
      rb1 = *(const float4*)(gB1 + k0);
    }
#pragma unroll
    for (int kk = 0; kk < BK; ++kk) {
      float4 av  = *(const float4*)&sA[cur][kk][tm * 4];
      float4 bv0 = *(const float4*)&sB[cur][kk][tn * 4];
      float4 bv1 = *(const float4*)&sB[cur][kk][64 + tn * 4];
      float a;
#pragma unroll
      for (int i = 0; i < 4; ++i) {
        a = (i == 0) ? av.x : (i == 1) ? av.y : (i == 2) ? av.z : av.w;
        acc[i][0].x = fmaf(a, bv0.x, acc[i][0].x);
        acc[i][0].y = fmaf(a, bv0.y, acc[i][0].y);
        acc[i][0].z = fmaf(a, bv0.z, acc[i][0].z);
        acc[i][0].w = fmaf(a, bv0.w, acc[i][0].w);
        acc[i][1].x = fmaf(a, bv1.x, acc[i][1].x);
        acc[i][1].y = fmaf(a, bv1.y, acc[i][1].y);
        acc[i][1].z = fmaf(a, bv1.z, acc[i][1].z);
        acc[i][1].w = fmaf(a, bv1.w, acc[i][1].w);
      }
    }
    if (kt + 1 < NKT) {
      __syncthreads();
      sA[nxt][ac + 0][ar] = ra.x;  sA[nxt][ac + 1][ar] = ra.y;
      sA[nxt][ac + 2][ar] = ra.z;  sA[nxt][ac + 3][ar] = ra.w;
      sB[nxt][ac + 0][ar] = rb0.x; sB[nxt][ac + 1][ar] = rb0.y;
      sB[nxt][ac + 2][ar] = rb0.z; sB[nxt][ac + 3][ar] = rb0.w;
      sB[nxt][ac + 0][64 + ar] = rb1.x; sB[nxt][ac + 1][64 + ar] = rb1.y;
      sB[nxt][ac + 2][64 + ar] = rb1.z; sB[nxt][ac + 3][64 + ar] = rb1.w;
      __syncthreads();
    }
  }

#pragma unroll
  for (int i = 0; i < 4; ++i) {
    float* o = prob + (size_t)(row0 + tm * 4 + i) * PROB_LD + col0;
    *(float4*)(o + tn * 4)      = acc[i][0];
    *(float4*)(o + 64 + tn * 4) = acc[i][1];
  }
}

// ---------------------------------------------------------------------------
// Kernel 2: per-row top-10 (one wave per row; row cached in LDS).
// ---------------------------------------------------------------------------
__global__ __launch_bounds__(256) void k_topk(
    const float* __restrict__ prob, int* __restrict__ topk)
{
  __shared__ float srow[4][PROB_LD];
  const int tid  = threadIdx.x;
  const int wave = tid >> 6, lane = tid & 63;
  const int row  = blockIdx.x * 4 + wave;

  const float* p = prob + (size_t)row * PROB_LD;
#pragma unroll
  for (int i = 0; i < PROB_LD / 64; ++i) {
    const int j = lane + i * 64;
    srow[wave][j] = (j < NPROTO) ? p[j] : -FLT_MAX;
  }

  for (int kk = 0; kk < KSEL; ++kk) {
    float bv = -FLT_MAX;
    int   bi = 0x7fffffff;
#pragma unroll
    for (int i = 0; i < PROB_LD / 64; ++i) {
      const int j = lane + i * 64;
      float v = srow[wave][j];
      if (v > bv || (v == bv && j < bi)) { bv = v; bi = j; }
    }
#pragma unroll
    for (int off = 32; off; off >>= 1) {
      float ov = __shfl_down(bv, off);
      int   oi = __shfl_down(bi, off);
      if (ov > bv || (ov == bv && oi < bi)) { bv = ov; bi = oi; }
    }
    bi = __shfl(bi, 0);
    if (lane == 0) topk[(size_t)row * KSEL + kk] = bi;
    srow[wave][bi] = -FLT_MAX;
  }
}

// ---------------------------------------------------------------------------
// Kernel 3: dense zero-fill of the whole output + zero the bucket counters.
// ---------------------------------------------------------------------------
__global__ __launch_bounds__(256) void k_zero(
    float* __restrict__ out, int* __restrict__ counts)
{
  const int tid = blockIdx.x * 256 + threadIdx.x;
  const float4 z = {0.f, 0.f, 0.f, 0.f};
  float4* o4 = reinterpret_cast<float4*>(out);
  const int n4 = (B_ROWS * NCLASSES) / 4;            // 10.24M
  for (int i = tid; i < n4; i += 256 * 4096) o4[i] = z;
  if (blockIdx.x == 0) {
    for (int i = threadIdx.x; i < NPROTO; i += 256) counts[i] = 0;
  }
}

// ---------------------------------------------------------------------------
// Kernel 4: invert (row -> protos) into per-proto row buckets.
// Bucket order is atomic-race dependent, but output is order-invariant.
// ---------------------------------------------------------------------------
__global__ __launch_bounds__(256) void k_build(
    const int* __restrict__ topk, int* __restrict__ counts,
    int* __restrict__ buckets)
{
  const int g = blockIdx.x * 256 + threadIdx.x;
  if (g >= NPAIRS) return;
  const int p   = topk[g];
  const int row = g / KSEL;
  const int pos = atomicAdd(&counts[p], 1);
  if (pos < CAP) buckets[p * CAP + pos] = row;
}

// ---------------------------------------------------------------------------
// Kernel 5: one block per proto. Stage its 10 text rows in LDS, normalize
// in-kernel (folding exp(logit_scale)), then for each bucketed row compute
// the 10 dots (one row per wave, contiguous b128 LDS reads, butterfly reduce).
// ---------------------------------------------------------------------------
__global__ __launch_bounds__(256) void k_compute(
    const float* __restrict__ img, const float* __restrict__ text,
    const int* __restrict__ counts, const int* __restrict__ buckets,
    const float* __restrict__ logit_scale, float* __restrict__ out)
{
  __shared__ float stext[KSEL * DIM];   // 20 KB, [j][d]
  __shared__ float sfac[KSEL];

  const int p    = blockIdx.x;
  const int tid  = threadIdx.x;
  const int wave = tid >> 6, lane = tid & 63;

  // stage raw text rows p*10 .. p*10+9 (1280 float4, 5 per thread)
  {
    const float4* src = reinterpret_cast<const float4*>(text + (size_t)p * KSEL * DIM);
    float4* dst = reinterpret_cast<float4*>(stext);
#pragma unroll
    for (int i = 0; i < 5; ++i) dst[tid + i * 256] = src[tid + i * 256];
  }
  __syncthreads();

  // norms: wave w handles j = w, w+4, w+8
  const float scale = expf(logit_scale[0]);
#pragma unroll
  for (int j = wave; j < KSEL; j += 4) {
    const float4* t4 = reinterpret_cast<const float4*>(stext + j * DIM);
    float4 v0 = t4[lane], v1 = t4[64 + lane];
    float s = 0.f;
    s = fmaf(v0.x, v0.x, s); s = fmaf(v0.y, v0.y, s);
    s = fmaf(v0.z, v0.z, s); s = fmaf(v0.w, v0.w, s);
    s = fmaf(v1.x, v1.x, s); s = fmaf(v1.y, v1.y, s);
    s = fmaf(v1.z, v1.z, s); s = fmaf(v1.w, v1.w, s);
#pragma unroll
    for (int off = 32; off; off >>= 1) s += __shfl_down(s, off);
    if (lane == 0) sfac[j] = scale / sqrtf(s);
  }
  __syncthreads();

  // rescale staged text by sfac[j]
  {
    float4* st4 = reinterpret_cast<float4*>(stext);
#pragma unroll
    for (int i = 0; i < 5; ++i) {
      const int idx = tid + i * 256;        // 0..1279
      const float f = sfac[idx >> 7];
      float4 v = st4[idx];
      v.x *= f; v.y *= f; v.z *= f; v.w *= f;
      st4[idx] = v;
    }
  }
  __syncthreads();

  const int n = min(counts[p], CAP);
  const float4* st4 = reinterpret_cast<const float4*>(stext);

  for (int i = wave; i < n; i += 4) {
    const int row = buckets[p * CAP + i];
    const float4* a4 = reinterpret_cast<const float4*>(img + (size_t)row * DIM);
    const float4 a0 = a4[lane], a1 = a4[64 + lane];

    float acc[KSEL];
#pragma unroll
    for (int j = 0; j < KSEL; ++j) {
      const float4 b0 = st4[j * 128 + lane];
      const float4 b1 = st4[j * 128 + 64 + lane];
      float s = 0.f;
      s = fmaf(a0.x, b0.x, s); s = fmaf(a0.y, b0.y, s);
      s = fmaf(a0.z, b0.z, s); s = fmaf(a0.w, b0.w, s);
      s = fmaf(a1.x, b1.x, s); s = fmaf(a1.y, b1.y, s);
      s = fmaf(a1.z, b1.z, s); s = fmaf(a1.w, b1.w, s);
      acc[j] = s;
    }
#pragma unroll
    for (int j = 0; j < KSEL; ++j) {
#pragma unroll
      for (int off = 32; off; off >>= 1)
        acc[j] += __shfl_xor(acc[j], off);
    }
    // lane c (c<10) writes acc[c] -- compile-time select chain
    float v = acc[0];
#pragma unroll
    for (int j = 1; j < KSEL; ++j) if (lane == j) v = acc[j];
    if (lane < KSEL)
      out[(size_t)row * NCLASSES + p * KSEL + lane] = v;
  }
}

// ---------------------------------------------------------------------------
extern "C" void kernel_launch(void* const* d_in, const int* in_sizes, int n_in,
                              void* d_out, int out_size, void* d_ws, size_t ws_size,
                              hipStream_t stream) {
  const float* img    = (const float*)d_in[0];
  const float* proto  = (const float*)d_in[1];
  const float* text   = (const float*)d_in[2];
  const float* lscale = (const float*)d_in[3];

  // prob scratch lives INSIDE d_out (16.8 MB); zeroed after k_topk reads it.
  float* prob = (float*)d_out;
  float* out  = (float*)d_out;

  // ws layout (1.2 MB total)
  int* topk    = (int*)d_ws;                                   // 163840 B
  int* counts  = (int*)((char*)d_ws + 163840);                 // 4096 B
  int* buckets = (int*)((char*)d_ws + 167936);                 // 1000*CAP*4

  k_gemm<<<dim3(B_ROWS / BM, (NPROTO + BN - 1) / BN), 256, 0, stream>>>(img, proto, prob);
  k_topk<<<B_ROWS / 4, 256, 0, stream>>>(prob, topk);
  k_zero<<<4096, 256, 0, stream>>>(out, counts);
  k_build<<<(NPAIRS + 255) / 256, 256, 0, stream>>>(topk, counts, buckets);
  k_compute<<<NPROTO, 256, 0, stream>>>(img, text, counts, buckets, lscale, out);
}

// Round 4
// 147.681 us; speedup vs baseline: 4.1446x; 1.0931x over previous
//
#include <hip/hip_runtime.h>
#include <cfloat>
#include <math.h>

// Problem constants (fixed by the reference)
#define B_ROWS   4096
#define DIM      512
#define NPROTO   1000
#define NPROTO_P 1024              // padded proto count for MFMA GEMM
#define NCLASSES 10000
#define KSEL     10
#define KCAND    16                // approx candidates rescored in f32
#define NPAIRS   (B_ROWS * KSEL)
#define CAP      256               // bucket capacity (avg 41)
#define PROB_LD  1024

// MFMA GEMM tiling
#define GBM 64
#define GBN 128
#define GBK 32
#define ALD 40                     // padded LDS row stride (bf16 elems)

typedef short s16x8 __attribute__((ext_vector_type(8)));
typedef float f32x4 __attribute__((ext_vector_type(4)));

static __device__ __forceinline__ unsigned short f2bf(float f) {
  unsigned int x = __float_as_uint(f);
  return (unsigned short)((x + 0x7fffu + ((x >> 16) & 1u)) >> 16);  // RNE
}

// ---------------------------------------------------------------------------
// Kernel 0: convert img + proto to bf16 (proto zero-padded to 1024 rows).
// ---------------------------------------------------------------------------
__global__ __launch_bounds__(256) void k_convert(
    const float* __restrict__ img, const float* __restrict__ proto,
    short* __restrict__ imgb, short* __restrict__ protb)
{
  const int u = blockIdx.x * 256 + threadIdx.x;   // one unit = 8 elems
  const int IMGC = (B_ROWS * DIM) / 8;            // 262144
  const int PROC = (NPROTO_P * DIM) / 8;          // 65536
  if (u < IMGC) {
    const float4* s = reinterpret_cast<const float4*>(img) + (size_t)u * 2;
    float4 v0 = s[0], v1 = s[1];
    s16x8 r;
    r[0]=f2bf(v0.x); r[1]=f2bf(v0.y); r[2]=f2bf(v0.z); r[3]=f2bf(v0.w);
    r[4]=f2bf(v1.x); r[5]=f2bf(v1.y); r[6]=f2bf(v1.z); r[7]=f2bf(v1.w);
    *reinterpret_cast<s16x8*>(imgb + (size_t)u * 8) = r;
  } else if (u < IMGC + PROC) {
    const int v = u - IMGC;
    s16x8 r = (s16x8)0;
    if (v * 8 < NPROTO * DIM) {
      const float4* s = reinterpret_cast<const float4*>(proto) + (size_t)v * 2;
      float4 v0 = s[0], v1 = s[1];
      r[0]=f2bf(v0.x); r[1]=f2bf(v0.y); r[2]=f2bf(v0.z); r[3]=f2bf(v0.w);
      r[4]=f2bf(v1.x); r[5]=f2bf(v1.y); r[6]=f2bf(v1.z); r[7]=f2bf(v1.w);
    }
    *reinterpret_cast<s16x8*>(protb + (size_t)v * 8) = r;
  }
}

// ---------------------------------------------------------------------------
// Kernel 1: prob = imgb @ protb.T via 16x16x32 bf16 MFMA.
// 64x128 tile, 4 waves (2x2), each wave 32x64 = 2x4 fragments. LDS stride 40
// (2-way bank alias only = free). 2-barrier K-loop, reg-staged prefetch.
// ---------------------------------------------------------------------------
__global__ __launch_bounds__(256) void k_gemm_mfma(
    const short* __restrict__ imgb, const short* __restrict__ protb,
    float* __restrict__ prob)
{
  __shared__ short Al[GBM * ALD];   // 5 KB
  __shared__ short Bl[GBN * ALD];   // 10 KB

  const int tid  = threadIdx.x;
  const int lane = tid & 63, wave = tid >> 6;
  const int wr = wave >> 1, wc = wave & 1;
  const int row0 = blockIdx.x * GBM;
  const int col0 = blockIdx.y * GBN;

  const int sr = tid >> 2;          // staging row 0..63
  const int sc = (tid & 3) * 8;     // staging k-col 0,8,16,24

  const short* gA  = imgb  + (size_t)(row0 + sr) * DIM + sc;
  const short* gB0 = protb + (size_t)(col0 + sr) * DIM + sc;
  const short* gB1 = protb + (size_t)(col0 + 64 + sr) * DIM + sc;

  s16x8 ra  = *(const s16x8*)gA;
  s16x8 rb0 = *(const s16x8*)gB0;
  s16x8 rb1 = *(const s16x8*)gB1;

  f32x4 acc[2][4];
#pragma unroll
  for (int m = 0; m < 2; ++m)
#pragma unroll
    for (int n = 0; n < 4; ++n) acc[m][n] = (f32x4)0.f;

  const int kg = lane >> 4;   // k-group 0..3 (8 elems each)
  const int fr = lane & 15;   // fragment row/col

  for (int kt = 0; kt < DIM / GBK; ++kt) {
    *(s16x8*)&Al[sr * ALD + sc]        = ra;
    *(s16x8*)&Bl[sr * ALD + sc]        = rb0;
    *(s16x8*)&Bl[(64 + sr) * ALD + sc] = rb1;
    __syncthreads();

    if (kt + 1 < DIM / GBK) {
      const int k0 = (kt + 1) * GBK;
      ra  = *(const s16x8*)(gA + k0);
      rb0 = *(const s16x8*)(gB0 + k0);
      rb1 = *(const s16x8*)(gB1 + k0);
    }

    s16x8 af[2], bf[4];
#pragma unroll
    for (int m = 0; m < 2; ++m)
      af[m] = *(const s16x8*)&Al[(wr * 32 + m * 16 + fr) * ALD + kg * 8];
#pragma unroll
    for (int n = 0; n < 4; ++n)
      bf[n] = *(const s16x8*)&Bl[(wc * 64 + n * 16 + fr) * ALD + kg * 8];
#pragma unroll
    for (int m = 0; m < 2; ++m)
#pragma unroll
      for (int n = 0; n < 4; ++n)
        acc[m][n] = __builtin_amdgcn_mfma_f32_16x16x32_bf16(
            af[m], bf[n], acc[m][n], 0, 0, 0);
    __syncthreads();
  }

  // C/D layout (m89/m91): col = lane&15, row = (lane>>4)*4 + reg
#pragma unroll
  for (int m = 0; m < 2; ++m)
#pragma unroll
    for (int n = 0; n < 4; ++n) {
      const int r = row0 + wr * 32 + m * 16 + (lane >> 4) * 4;
      const int c = col0 + wc * 64 + n * 16 + fr;
#pragma unroll
      for (int reg = 0; reg < 4; ++reg)
        prob[(size_t)(r + reg) * PROB_LD + c] = acc[m][n][reg];
    }
}

// ---------------------------------------------------------------------------
// Kernel 2: per-row top-16 candidates from approx prob (one wave per row).
// ---------------------------------------------------------------------------
__global__ __launch_bounds__(256) void k_topk(
    const float* __restrict__ prob, int* __restrict__ cand)
{
  __shared__ float srow[4][PROB_LD];
  const int tid  = threadIdx.x;
  const int wave = tid >> 6, lane = tid & 63;
  const int row  = blockIdx.x * 4 + wave;

  const float* p = prob + (size_t)row * PROB_LD;
#pragma unroll
  for (int i = 0; i < PROB_LD / 64; ++i) {
    const int j = lane + i * 64;
    srow[wave][j] = (j < NPROTO) ? p[j] : -FLT_MAX;
  }

  for (int kk = 0; kk < KCAND; ++kk) {
    float bv = -FLT_MAX;
    int   bi = 0x7fffffff;
#pragma unroll
    for (int i = 0; i < PROB_LD / 64; ++i) {
      const int j = lane + i * 64;
      float v = srow[wave][j];
      if (v > bv || (v == bv && j < bi)) { bv = v; bi = j; }
    }
#pragma unroll
    for (int off = 32; off; off >>= 1) {
      float ov = __shfl_down(bv, off);
      int   oi = __shfl_down(bi, off);
      if (ov > bv || (ov == bv && oi < bi)) { bv = ov; bi = oi; }
    }
    bi = __shfl(bi, 0);
    if (lane == 0) cand[(size_t)row * KCAND + kk] = bi;
    srow[wave][bi] = -FLT_MAX;
  }
}

// ---------------------------------------------------------------------------
// Kernel 3: exact f32 rescore of the 16 candidates; keep the top-10 set.
// One wave per row.
// ---------------------------------------------------------------------------
__global__ __launch_bounds__(256) void k_rescore(
    const float* __restrict__ img, const float* __restrict__ proto,
    const int* __restrict__ cand, int* __restrict__ topk)
{
  const int tid  = threadIdx.x;
  const int wave = tid >> 6, lane = tid & 63;
  const int row  = blockIdx.x * 4 + wave;

  const float4* a4 = reinterpret_cast<const float4*>(img + (size_t)row * DIM);
  const float4 a0 = a4[lane], a1 = a4[64 + lane];

  int   ci[KCAND];
  float dv[KCAND];
#pragma unroll
  for (int j = 0; j < KCAND; ++j) {
    ci[j] = cand[(size_t)row * KCAND + j];          // wave-uniform broadcast
    const float4* p4 = reinterpret_cast<const float4*>(proto + (size_t)ci[j] * DIM);
    const float4 b0 = p4[lane], b1 = p4[64 + lane];
    float s = 0.f;
    s = fmaf(a0.x, b0.x, s); s = fmaf(a0.y, b0.y, s);
    s = fmaf(a0.z, b0.z, s); s = fmaf(a0.w, b0.w, s);
    s = fmaf(a1.x, b1.x, s); s = fmaf(a1.y, b1.y, s);
    s = fmaf(a1.z, b1.z, s); s = fmaf(a1.w, b1.w, s);
#pragma unroll
    for (int off = 32; off; off >>= 1) s += __shfl_xor(s, off);
    dv[j] = s;
  }

  unsigned picked = 0;
  for (int kk = 0; kk < KSEL; ++kk) {
    float bv = -FLT_MAX;
    int   bj = 0;
#pragma unroll
    for (int j = 0; j < KCAND; ++j)
      if (!((picked >> j) & 1u) && dv[j] > bv) { bv = dv[j]; bj = j; }
    picked |= 1u << bj;
    if (lane == kk) topk[(size_t)row * KSEL + kk] = ci[bj];
  }
}

// ---------------------------------------------------------------------------
// Kernel 4: dense zero-fill of the whole output + zero the bucket counters.
// ---------------------------------------------------------------------------
__global__ __launch_bounds__(256) void k_zero(
    float* __restrict__ out, int* __restrict__ counts)
{
  const int tid = blockIdx.x * 256 + threadIdx.x;
  const float4 z = {0.f, 0.f, 0.f, 0.f};
  float4* o4 = reinterpret_cast<float4*>(out);
  const int n4 = (B_ROWS * NCLASSES) / 4;
  for (int i = tid; i < n4; i += 256 * 4096) o4[i] = z;
  if (blockIdx.x == 0)
    for (int i = threadIdx.x; i < NPROTO; i += 256) counts[i] = 0;
}

// ---------------------------------------------------------------------------
// Kernel 5: invert (row -> protos) into per-proto row buckets.
// ---------------------------------------------------------------------------
__global__ __launch_bounds__(256) void k_build(
    const int* __restrict__ topk, int* __restrict__ counts,
    int* __restrict__ buckets)
{
  const int g = blockIdx.x * 256 + threadIdx.x;
  if (g >= NPAIRS) return;
  const int p   = topk[g];
  const int row = g / KSEL;
  const int pos = atomicAdd(&counts[p], 1);
  if (pos < CAP) buckets[p * CAP + pos] = row;
}

// ---------------------------------------------------------------------------
// Kernel 6: one block per proto; stage + normalize its 10 text rows in LDS,
// then compute the 10 dots for each bucketed image row.
// ---------------------------------------------------------------------------
__global__ __launch_bounds__(256) void k_compute(
    const float* __restrict__ img, const float* __restrict__ text,
    const int* __restrict__ counts, const int* __restrict__ buckets,
    const float* __restrict__ logit_scale, float* __restrict__ out)
{
  __shared__ float stext[KSEL * DIM];
  __shared__ float sfac[KSEL];

  const int p    = blockIdx.x;
  const int tid  = threadIdx.x;
  const int wave = tid >> 6, lane = tid & 63;

  {
    const float4* src = reinterpret_cast<const float4*>(text + (size_t)p * KSEL * DIM);
    float4* dst = reinterpret_cast<float4*>(stext);
#pragma unroll
    for (int i = 0; i < 5; ++i) dst[tid + i * 256] = src[tid + i * 256];
  }
  __syncthreads();

  const float scale = expf(logit_scale[0]);
#pragma unroll
  for (int j = wave; j < KSEL; j += 4) {
    const float4* t4 = reinterpret_cast<const float4*>(stext + j * DIM);
    float4 v0 = t4[lane], v1 = t4[64 + lane];
    float s = 0.f;
    s = fmaf(v0.x, v0.x, s); s = fmaf(v0.y, v0.y, s);
    s = fmaf(v0.z, v0.z, s); s = fmaf(v0.w, v0.w, s);
    s = fmaf(v1.x, v1.x, s); s = fmaf(v1.y, v1.y, s);
    s = fmaf(v1.z, v1.z, s); s = fmaf(v1.w, v1.w, s);
#pragma unroll
    for (int off = 32; off; off >>= 1) s += __shfl_down(s, off);
    if (lane == 0) sfac[j] = scale / sqrtf(s);
  }
  __syncthreads();

  {
    float4* st4 = reinterpret_cast<float4*>(stext);
#pragma unroll
    for (int i = 0; i < 5; ++i) {
      const int idx = tid + i * 256;
      const float f = sfac[idx >> 7];
      float4 v = st4[idx];
      v.x *= f; v.y *= f; v.z *= f; v.w *= f;
      st4[idx] = v;
    }
  }
  __syncthreads();

  const int n = min(counts[p], CAP);
  const float4* st4 = reinterpret_cast<const float4*>(stext);

  for (int i = wave; i < n; i += 4) {
    const int row = buckets[p * CAP + i];
    const float4* a4 = reinterpret_cast<const float4*>(img + (size_t)row * DIM);
    const float4 a0 = a4[lane], a1 = a4[64 + lane];

    float acc[KSEL];
#pragma unroll
    for (int j = 0; j < KSEL; ++j) {
      const float4 b0 = st4[j * 128 + lane];
      const float4 b1 = st4[j * 128 + 64 + lane];
      float s = 0.f;
      s = fmaf(a0.x, b0.x, s); s = fmaf(a0.y, b0.y, s);
      s = fmaf(a0.z, b0.z, s); s = fmaf(a0.w, b0.w, s);
      s = fmaf(a1.x, b1.x, s); s = fmaf(a1.y, b1.y, s);
      s = fmaf(a1.z, b1.z, s); s = fmaf(a1.w, b1.w, s);
      acc[j] = s;
    }
#pragma unroll
    for (int j = 0; j < KSEL; ++j) {
#pragma unroll
      for (int off = 32; off; off >>= 1)
        acc[j] += __shfl_xor(acc[j], off);
    }
    float v = acc[0];
#pragma unroll
    for (int j = 1; j < KSEL; ++j) if (lane == j) v = acc[j];
    if (lane < KSEL)
      out[(size_t)row * NCLASSES + p * KSEL + lane] = v;
  }
}

// ---------------------------------------------------------------------------
extern "C" void kernel_launch(void* const* d_in, const int* in_sizes, int n_in,
                              void* d_out, int out_size, void* d_ws, size_t ws_size,
                              hipStream_t stream) {
  const float* img    = (const float*)d_in[0];
  const float* proto  = (const float*)d_in[1];
  const float* text   = (const float*)d_in[2];
  const float* lscale = (const float*)d_in[3];

  // Scratch inside d_out (all overwritten by k_zero afterwards, same stream):
  //   [0, 16.8MB)  prob f32 4096x1024
  //   [32MB, 36MB) imgb bf16 4096x512
  //   [40MB, 41MB) protb bf16 1024x512
  float* prob  = (float*)d_out;
  short* imgb  = (short*)((char*)d_out + (32u << 20));
  short* protb = (short*)((char*)d_out + (40u << 20));
  float* out   = (float*)d_out;

  // ws layout (~1.45 MB)
  int* cand    = (int*)d_ws;                                   // 4096*16*4
  int* topk    = (int*)((char*)d_ws + 262144);                 // 4096*10*4
  int* counts  = (int*)((char*)d_ws + 262144 + 163840);        // 1000*4
  int* buckets = (int*)((char*)d_ws + 262144 + 163840 + 4096); // 1000*256*4

  k_convert<<<(((B_ROWS + NPROTO_P) * DIM / 8) + 255) / 256, 256, 0, stream>>>(
      img, proto, imgb, protb);
  k_gemm_mfma<<<dim3(B_ROWS / GBM, NPROTO_P / GBN), 256, 0, stream>>>(
      imgb, protb, prob);
  k_topk<<<B_ROWS / 4, 256, 0, stream>>>(prob, cand);
  k_rescore<<<B_ROWS / 4, 256, 0, stream>>>(img, proto, cand, topk);
  k_zero<<<4096, 256, 0, stream>>>(out, counts);
  k_build<<<(NPAIRS + 255) / 256, 256, 0, stream>>>(topk, counts, buckets);
  k_compute<<<NPROTO, 256, 0, stream>>>(img, text, counts, buckets, lscale, out);
}

// Round 6
// 140.456 us; speedup vs baseline: 4.3578x; 1.0514x over previous
//
#include <hip/hip_runtime.h>
#include <cfloat>
#include <math.h>

// Problem constants (fixed by the reference)
#define B_ROWS   4096
#define DIM      512
#define NPROTO   1000
#define NPROTO_P 1024              // padded proto count for MFMA GEMM
#define NCLASSES 10000
#define KSEL     10
#define KCAND    16                // approx candidates rescored in f32
#define NPAIRS   (B_ROWS * KSEL)
#define CAP      256               // bucket capacity (avg 41)
#define PROB_LD  1024

// d_out scratch layout (bytes). All of it is re-zeroed before k_compute.
//   [0, 16777216)          prob f32 4096x1024
//   [16777216, 20971520)   imgb bf16 4096x512
//   [20971520, 22020096)   protb bf16 1024x512
//   gemm zeroes [22020096, 163840000); rescore zeroes [0, 22020096)
#define IMGB_OFF   16777216u
#define PROTB_OFF  20971520u
#define ZLO_BYTES  22020096u
#define OUT_BYTES  163840000u
#define ZLO_N4     (ZLO_BYTES / 16)                 // 1376256 f32x4
#define ZHI_N4     ((OUT_BYTES - ZLO_BYTES) / 16)   // 8863744 f32x4

// MFMA GEMM tiling
#define GBM 64
#define GBN 128
#define GBK 32
#define ALD 40                     // padded LDS row stride (bf16 elems)

typedef short s16x8 __attribute__((ext_vector_type(8)));
typedef float f32x4 __attribute__((ext_vector_type(4)));

static __device__ __forceinline__ unsigned short f2bf(float f) {
  unsigned int x = __float_as_uint(f);
  return (unsigned short)((x + 0x7fffu + ((x >> 16) & 1u)) >> 16);  // RNE
}

// ---------------------------------------------------------------------------
// Kernel 0: convert img + proto to bf16 (proto zero-padded to 1024 rows);
// block 0 also zeroes the bucket counters.
// ---------------------------------------------------------------------------
__global__ __launch_bounds__(256) void k_convert(
    const float* __restrict__ img, const float* __restrict__ proto,
    short* __restrict__ imgb, short* __restrict__ protb,
    int* __restrict__ counts)
{
  const int u = blockIdx.x * 256 + threadIdx.x;   // one unit = 8 elems
  const int IMGC = (B_ROWS * DIM) / 8;            // 262144
  const int PROC = (NPROTO_P * DIM) / 8;          // 65536
  if (u < IMGC) {
    const float4* s = reinterpret_cast<const float4*>(img) + (size_t)u * 2;
    float4 v0 = s[0], v1 = s[1];
    s16x8 r;
    r[0]=f2bf(v0.x); r[1]=f2bf(v0.y); r[2]=f2bf(v0.z); r[3]=f2bf(v0.w);
    r[4]=f2bf(v1.x); r[5]=f2bf(v1.y); r[6]=f2bf(v1.z); r[7]=f2bf(v1.w);
    *reinterpret_cast<s16x8*>(imgb + (size_t)u * 8) = r;
  } else if (u < IMGC + PROC) {
    const int v = u - IMGC;
    s16x8 r = (s16x8)0;
    if (v * 8 < NPROTO * DIM) {
      const float4* s = reinterpret_cast<const float4*>(proto) + (size_t)v * 2;
      float4 v0 = s[0], v1 = s[1];
      r[0]=f2bf(v0.x); r[1]=f2bf(v0.y); r[2]=f2bf(v0.z); r[3]=f2bf(v0.w);
      r[4]=f2bf(v1.x); r[5]=f2bf(v1.y); r[6]=f2bf(v1.z); r[7]=f2bf(v1.w);
    }
    *reinterpret_cast<s16x8*>(protb + (size_t)v * 8) = r;
  }
  if (blockIdx.x == 0) {
    for (int i = threadIdx.x; i < NPROTO; i += 256) counts[i] = 0;
  }
}

// ---------------------------------------------------------------------------
// Kernel 1: prob = imgb @ protb.T via 16x16x32 bf16 MFMA, with the dense
// zero-fill of out[ZLO..end] fused into the K-loop as non-temporal stores.
// ---------------------------------------------------------------------------
__global__ __launch_bounds__(256) void k_gemm_mfma(
    const short* __restrict__ imgb, const short* __restrict__ protb,
    float* __restrict__ prob, f32x4* __restrict__ zhi)
{
  __shared__ short Al[GBM * ALD];   // 5 KB
  __shared__ short Bl[GBN * ALD];   // 10 KB

  const int tid  = threadIdx.x;
  const int lane = tid & 63, wave = tid >> 6;
  const int wr = wave >> 1, wc = wave & 1;
  const int row0 = blockIdx.x * GBM;
  const int col0 = blockIdx.y * GBN;
  // flat thread id over the whole grid (for the fused zero)
  const int gth = (blockIdx.y * gridDim.x + blockIdx.x) * 256 + tid; // 0..131071

  const int sr = tid >> 2;          // staging row 0..63
  const int sc = (tid & 3) * 8;     // staging k-col 0,8,16,24

  const short* gA  = imgb  + (size_t)(row0 + sr) * DIM + sc;
  const short* gB0 = protb + (size_t)(col0 + sr) * DIM + sc;
  const short* gB1 = protb + (size_t)(col0 + 64 + sr) * DIM + sc;

  s16x8 ra  = *(const s16x8*)gA;
  s16x8 rb0 = *(const s16x8*)gB0;
  s16x8 rb1 = *(const s16x8*)gB1;

  f32x4 acc[2][4];
#pragma unroll
  for (int m = 0; m < 2; ++m)
#pragma unroll
    for (int n = 0; n < 4; ++n) acc[m][n] = (f32x4)0.f;

  const int kg = lane >> 4;   // k-group 0..3
  const int fr = lane & 15;   // fragment row/col
  const f32x4 z4 = (f32x4)0.f;

  for (int kt = 0; kt < DIM / GBK; ++kt) {
    *(s16x8*)&Al[sr * ALD + sc]        = ra;
    *(s16x8*)&Bl[sr * ALD + sc]        = rb0;
    *(s16x8*)&Bl[(64 + sr) * ALD + sc] = rb1;
    __syncthreads();

    if (kt + 1 < DIM / GBK) {
      const int k0 = (kt + 1) * GBK;
      ra  = *(const s16x8*)(gA + k0);
      rb0 = *(const s16x8*)(gB0 + k0);
      rb1 = *(const s16x8*)(gB1 + k0);
    }

    s16x8 af[2], bf[4];
#pragma unroll
    for (int m = 0; m < 2; ++m)
      af[m] = *(const s16x8*)&Al[(wr * 32 + m * 16 + fr) * ALD + kg * 8];
#pragma unroll
    for (int n = 0; n < 4; ++n)
      bf[n] = *(const s16x8*)&Bl[(wc * 64 + n * 16 + fr) * ALD + kg * 8];
#pragma unroll
    for (int m = 0; m < 2; ++m)
#pragma unroll
      for (int n = 0; n < 4; ++n)
        acc[m][n] = __builtin_amdgcn_mfma_f32_16x16x32_bf16(
            af[m], bf[n], acc[m][n], 0, 0, 0);

    // fused zero-fill slice for this kt (fire-and-forget, non-temporal)
#pragma unroll
    for (int z = 0; z < 5; ++z) {
      const int i = kt * (131072 * 5) + z * 131072 + gth;
      if (i < ZHI_N4) __builtin_nontemporal_store(z4, zhi + i);
    }
    __syncthreads();
  }

  // C/D layout (m89/m91): col = lane&15, row = (lane>>4)*4 + reg
#pragma unroll
  for (int m = 0; m < 2; ++m)
#pragma unroll
    for (int n = 0; n < 4; ++n) {
      const int r = row0 + wr * 32 + m * 16 + (lane >> 4) * 4;
      const int c = col0 + wc * 64 + n * 16 + fr;
#pragma unroll
      for (int reg = 0; reg < 4; ++reg)
        prob[(size_t)(r + reg) * PROB_LD + c] = acc[m][n][reg];
    }
}

// ---------------------------------------------------------------------------
// Kernel 2: per-row top-16 candidates from approx prob (one wave per row).
// ---------------------------------------------------------------------------
__global__ __launch_bounds__(256) void k_topk(
    const float* __restrict__ prob, int* __restrict__ cand)
{
  __shared__ float srow[4][PROB_LD];
  const int tid  = threadIdx.x;
  const int wave = tid >> 6, lane = tid & 63;
  const int row  = blockIdx.x * 4 + wave;

  const float* p = prob + (size_t)row * PROB_LD;
#pragma unroll
  for (int i = 0; i < PROB_LD / 64; ++i) {
    const int j = lane + i * 64;
    srow[wave][j] = (j < NPROTO) ? p[j] : -FLT_MAX;
  }

  for (int kk = 0; kk < KCAND; ++kk) {
    float bv = -FLT_MAX;
    int   bi = 0x7fffffff;
#pragma unroll
    for (int i = 0; i < PROB_LD / 64; ++i) {
      const int j = lane + i * 64;
      float v = srow[wave][j];
      if (v > bv || (v == bv && j < bi)) { bv = v; bi = j; }
    }
#pragma unroll
    for (int off = 32; off; off >>= 1) {
      float ov = __shfl_down(bv, off);
      int   oi = __shfl_down(bi, off);
      if (ov > bv || (ov == bv && oi < bi)) { bv = ov; bi = oi; }
    }
    bi = __shfl(bi, 0);
    if (lane == 0) cand[(size_t)row * KCAND + kk] = bi;
    srow[wave][bi] = -FLT_MAX;
  }
}

// ---------------------------------------------------------------------------
// Kernel 3: exact f32 rescore of the 16 candidates -> top-10 set; also zeroes
// the scratch region out[0, ZLO) (prob + bf16 buffers), which is dead now.
// ---------------------------------------------------------------------------
__global__ __launch_bounds__(256) void k_rescore(
    const float* __restrict__ img, const float* __restrict__ proto,
    const int* __restrict__ cand, int* __restrict__ topk,
    f32x4* __restrict__ zlo)
{
  const int tid  = threadIdx.x;
  const int wave = tid >> 6, lane = tid & 63;
  const int row  = blockIdx.x * 4 + wave;

  const float4* a4 = reinterpret_cast<const float4*>(img + (size_t)row * DIM);
  const float4 a0 = a4[lane], a1 = a4[64 + lane];

  int   ci[KCAND];
  float dv[KCAND];
#pragma unroll
  for (int j = 0; j < KCAND; ++j) {
    ci[j] = cand[(size_t)row * KCAND + j];
    const float4* p4 = reinterpret_cast<const float4*>(proto + (size_t)ci[j] * DIM);
    const float4 b0 = p4[lane], b1 = p4[64 + lane];
    float s = 0.f;
    s = fmaf(a0.x, b0.x, s); s = fmaf(a0.y, b0.y, s);
    s = fmaf(a0.z, b0.z, s); s = fmaf(a0.w, b0.w, s);
    s = fmaf(a1.x, b1.x, s); s = fmaf(a1.y, b1.y, s);
    s = fmaf(a1.z, b1.z, s); s = fmaf(a1.w, b1.w, s);
#pragma unroll
    for (int off = 32; off; off >>= 1) s += __shfl_xor(s, off);
    dv[j] = s;
  }

  unsigned picked = 0;
  for (int kk = 0; kk < KSEL; ++kk) {
    float bv = -FLT_MAX;
    int   bj = 0;
#pragma unroll
    for (int j = 0; j < KCAND; ++j)
      if (!((picked >> j) & 1u) && dv[j] > bv) { bv = dv[j]; bj = j; }
    picked |= 1u << bj;
    if (lane == kk) topk[(size_t)row * KSEL + kk] = ci[bj];
  }

  // zero the dead scratch region [0, ZLO) of d_out
  const int gth = blockIdx.x * 256 + tid;       // 0..262143
  const f32x4 z4 = (f32x4)0.f;
#pragma unroll
  for (int z = 0; z < 6; ++z) {
    const int i = z * 262144 + gth;
    if (i < ZLO_N4) __builtin_nontemporal_store(z4, zlo + i);
  }
}

// ---------------------------------------------------------------------------
// Kernel 4: invert (row -> protos) into per-proto row buckets.
// ---------------------------------------------------------------------------
__global__ __launch_bounds__(256) void k_build(
    const int* __restrict__ topk, int* __restrict__ counts,
    int* __restrict__ buckets)
{
  const int g = blockIdx.x * 256 + threadIdx.x;
  if (g >= NPAIRS) return;
  const int p   = topk[g];
  const int row = g / KSEL;
  const int pos = atomicAdd(&counts[p], 1);
  if (pos < CAP) buckets[p * CAP + pos] = row;
}

// ---------------------------------------------------------------------------
// Kernel 5: one block per proto; stage + normalize its 10 text rows in LDS,
// then compute the 10 dots for each bucketed image row.
// ---------------------------------------------------------------------------
__global__ __launch_bounds__(256) void k_compute(
    const float* __restrict__ img, const float* __restrict__ text,
    const int* __restrict__ counts, const int* __restrict__ buckets,
    const float* __restrict__ logit_scale, float* __restrict__ out)
{
  __shared__ float stext[KSEL * DIM];
  __shared__ float sfac[KSEL];

  const int p    = blockIdx.x;
  const int tid  = threadIdx.x;
  const int wave = tid >> 6, lane = tid & 63;

  {
    const float4* src = reinterpret_cast<const float4*>(text + (size_t)p * KSEL * DIM);
    float4* dst = reinterpret_cast<float4*>(stext);
#pragma unroll
    for (int i = 0; i < 5; ++i) dst[tid + i * 256] = src[tid + i * 256];
  }
  __syncthreads();

  const float scale = expf(logit_scale[0]);
#pragma unroll
  for (int j = wave; j < KSEL; j += 4) {
    const float4* t4 = reinterpret_cast<const float4*>(stext + j * DIM);
    float4 v0 = t4[lane], v1 = t4[64 + lane];
    float s = 0.f;
    s = fmaf(v0.x, v0.x, s); s = fmaf(v0.y, v0.y, s);
    s = fmaf(v0.z, v0.z, s); s = fmaf(v0.w, v0.w, s);
    s = fmaf(v1.x, v1.x, s); s = fmaf(v1.y, v1.y, s);
    s = fmaf(v1.z, v1.z, s); s = fmaf(v1.w, v1.w, s);
#pragma unroll
    for (int off = 32; off; off >>= 1) s += __shfl_down(s, off);
    if (lane == 0) sfac[j] = scale / sqrtf(s);
  }
  __syncthreads();

  {
    float4* st4 = reinterpret_cast<float4*>(stext);
#pragma unroll
    for (int i = 0; i < 5; ++i) {
      const int idx = tid + i * 256;
      const float f = sfac[idx >> 7];
      float4 v = st4[idx];
      v.x *= f; v.y *= f; v.z *= f; v.w *= f;
      st4[idx] = v;
    }
  }
  __syncthreads();

  const int n = min(counts[p], CAP);
  const float4* st4 = reinterpret_cast<const float4*>(stext);

  for (int i = wave; i < n; i += 4) {
    const int row = buckets[p * CAP + i];
    const float4* a4 = reinterpret_cast<const float4*>(img + (size_t)row * DIM);
    const float4 a0 = a4[lane], a1 = a4[64 + lane];

    float acc[KSEL];
#pragma unroll
    for (int j = 0; j < KSEL; ++j) {
      const float4 b0 = st4[j * 128 + lane];
      const float4 b1 = st4[j * 128 + 64 + lane];
      float s = 0.f;
      s = fmaf(a0.x, b0.x, s); s = fmaf(a0.y, b0.y, s);
      s = fmaf(a0.z, b0.z, s); s = fmaf(a0.w, b0.w, s);
      s = fmaf(a1.x, b1.x, s); s = fmaf(a1.y, b1.y, s);
      s = fmaf(a1.z, b1.z, s); s = fmaf(a1.w, b1.w, s);
      acc[j] = s;
    }
#pragma unroll
    for (int j = 0; j < KSEL; ++j) {
#pragma unroll
      for (int off = 32; off; off >>= 1)
        acc[j] += __shfl_xor(acc[j], off);
    }
    float v = acc[0];
#pragma unroll
    for (int j = 1; j < KSEL; ++j) if (lane == j) v = acc[j];
    if (lane < KSEL)
      out[(size_t)row * NCLASSES + p * KSEL + lane] = v;
  }
}

// ---------------------------------------------------------------------------
extern "C" void kernel_launch(void* const* d_in, const int* in_sizes, int n_in,
                              void* d_out, int out_size, void* d_ws, size_t ws_size,
                              hipStream_t stream) {
  const float* img    = (const float*)d_in[0];
  const float* proto  = (const float*)d_in[1];
  const float* text   = (const float*)d_in[2];
  const float* lscale = (const float*)d_in[3];

  float*  prob  = (float*)d_out;
  short*  imgb  = (short*)((char*)d_out + IMGB_OFF);
  short*  protb = (short*)((char*)d_out + PROTB_OFF);
  f32x4*  zlo   = (f32x4*)d_out;
  f32x4*  zhi   = (f32x4*)((char*)d_out + ZLO_BYTES);
  float*  out   = (float*)d_out;

  // ws layout (~1.45 MB)
  int* cand    = (int*)d_ws;                                   // 4096*16*4
  int* topk    = (int*)((char*)d_ws + 262144);                 // 4096*10*4
  int* counts  = (int*)((char*)d_ws + 262144 + 163840);        // 1000*4
  int* buckets = (int*)((char*)d_ws + 262144 + 163840 + 4096); // 1000*256*4

  k_convert<<<(((B_ROWS + NPROTO_P) * DIM / 8) + 255) / 256, 256, 0, stream>>>(
      img, proto, imgb, protb, counts);
  k_gemm_mfma<<<dim3(B_ROWS / GBM, NPROTO_P / GBN), 256, 0, stream>>>(
      imgb, protb, prob, zhi);
  k_topk<<<B_ROWS / 4, 256, 0, stream>>>(prob, cand);
  k_rescore<<<B_ROWS / 4, 256, 0, stream>>>(img, proto, cand, topk, zlo);
  k_build<<<(NPAIRS + 255) / 256, 256, 0, stream>>>(topk, counts, buckets);
  k_compute<<<NPROTO, 256, 0, stream>>>(img, text, counts, buckets, lscale, out);
}

// Round 7
// 135.978 us; speedup vs baseline: 4.5013x; 1.0329x over previous
//
#include <hip/hip_runtime.h>
#include <cfloat>
#include <math.h>

// Problem constants (fixed by the reference)
#define B_ROWS   4096
#define DIM      512
#define NPROTO   1000
#define NPROTO_P 1024              // padded proto count for MFMA GEMM
#define NCLASSES 10000
#define KSEL     10
#define KCAND    16                // approx candidates rescored in f32
#define NPAIRS   (B_ROWS * KSEL)
#define CAP      256               // bucket capacity (avg 41)
#define PROB_LD  1024

// d_out scratch layout (bytes). All of d_out is re-zeroed before k_compute.
//   [0, 16777216)          prob f32 4096x1024
//   [16777216, 20971520)   imgb bf16 4096x512
//   [20971520, 22020096)   protb bf16 1024x512
// zlo = [0, ZLO) zeroed by rescore (after topk's last prob read).
// zhi = [ZLO, OUT) zeroed in shares by convert/gemm/topk/rescore/build,
// always as POST-compute NT stores with no barrier after (a barrier would
// force vmcnt(0) drain and serialize -- the R4/R6 lesson).
#define IMGB_OFF   16777216u
#define PROTB_OFF  20971520u
#define ZLO_BYTES  22020096u
#define OUT_BYTES  163840000u
#define ZLO_N4     (ZLO_BYTES / 16)                 // 1376256 f32x4
#define ZQ_TOTAL   ((OUT_BYTES - ZLO_BYTES) / 16)   // 8863744 f32x4

// zero shares (f32x4 units) within zhi
#define ZQ_CONV    1250000u   // 20 MB
#define ZQ_GEMM    4375000u   // 70 MB
#define ZQ_TOPK    1500000u   // 24 MB
#define ZQ_RESC     625000u   // 10 MB
#define ZQ_BUILD   (ZQ_TOTAL - ZQ_CONV - ZQ_GEMM - ZQ_TOPK - ZQ_RESC) // ~17.8MB
#define ZS_CONV    0u
#define ZS_GEMM    (ZS_CONV + ZQ_CONV)
#define ZS_TOPK    (ZS_GEMM + ZQ_GEMM)
#define ZS_RESC    (ZS_TOPK + ZQ_TOPK)
#define ZS_BUILD   (ZS_RESC + ZQ_RESC)

// MFMA GEMM tiling
#define GBM 64
#define GBN 128
#define GBK 32
#define ALD 40                     // padded LDS row stride (bf16 elems)

typedef short s16x8 __attribute__((ext_vector_type(8)));
typedef float f32x4 __attribute__((ext_vector_type(4)));

static __device__ __forceinline__ unsigned short f2bf(float f) {
  unsigned int x = __float_as_uint(f);
  return (unsigned short)((x + 0x7fffu + ((x >> 16) & 1u)) >> 16);  // RNE
}

static __device__ __forceinline__ void zero_share(
    f32x4* __restrict__ zhi, unsigned start, unsigned count,
    unsigned gth, unsigned nthreads)
{
  const f32x4 z4 = (f32x4)0.f;
  for (unsigned i = start + gth; i < start + count; i += nthreads)
    __builtin_nontemporal_store(z4, zhi + i);
}

// ---------------------------------------------------------------------------
// Kernel 0: convert img + proto to bf16 (proto zero-padded to 1024 rows);
// zeroes counts (block 0) + its zhi share.
// ---------------------------------------------------------------------------
__global__ __launch_bounds__(256) void k_convert(
    const float* __restrict__ img, const float* __restrict__ proto,
    short* __restrict__ imgb, short* __restrict__ protb,
    int* __restrict__ counts, f32x4* __restrict__ zhi)
{
  const int u = blockIdx.x * 256 + threadIdx.x;   // one unit = 8 elems
  const int IMGC = (B_ROWS * DIM) / 8;            // 262144
  const int PROC = (NPROTO_P * DIM) / 8;          // 65536
  if (u < IMGC) {
    const float4* s = reinterpret_cast<const float4*>(img) + (size_t)u * 2;
    float4 v0 = s[0], v1 = s[1];
    s16x8 r;
    r[0]=f2bf(v0.x); r[1]=f2bf(v0.y); r[2]=f2bf(v0.z); r[3]=f2bf(v0.w);
    r[4]=f2bf(v1.x); r[5]=f2bf(v1.y); r[6]=f2bf(v1.z); r[7]=f2bf(v1.w);
    *reinterpret_cast<s16x8*>(imgb + (size_t)u * 8) = r;
  } else if (u < IMGC + PROC) {
    const int v = u - IMGC;
    s16x8 r = (s16x8)0;
    if (v * 8 < NPROTO * DIM) {
      const float4* s = reinterpret_cast<const float4*>(proto) + (size_t)v * 2;
      float4 v0 = s[0], v1 = s[1];
      r[0]=f2bf(v0.x); r[1]=f2bf(v0.y); r[2]=f2bf(v0.z); r[3]=f2bf(v0.w);
      r[4]=f2bf(v1.x); r[5]=f2bf(v1.y); r[6]=f2bf(v1.z); r[7]=f2bf(v1.w);
    }
    *reinterpret_cast<s16x8*>(protb + (size_t)v * 8) = r;
  }
  if (blockIdx.x == 0)
    for (int i = threadIdx.x; i < NPROTO; i += 256) counts[i] = 0;

  zero_share(zhi, ZS_CONV, ZQ_CONV, u, 1280 * 256);
}

// ---------------------------------------------------------------------------
// Kernel 1: prob = imgb @ protb.T via 16x16x32 bf16 MFMA. zhi share is
// written POST-K-loop (no barrier follows -> stores drain async).
// ---------------------------------------------------------------------------
__global__ __launch_bounds__(256) void k_gemm_mfma(
    const short* __restrict__ imgb, const short* __restrict__ protb,
    float* __restrict__ prob, f32x4* __restrict__ zhi)
{
  __shared__ short Al[GBM * ALD];   // 5 KB
  __shared__ short Bl[GBN * ALD];   // 10 KB

  const int tid  = threadIdx.x;
  const int lane = tid & 63, wave = tid >> 6;
  const int wr = wave >> 1, wc = wave & 1;
  const int row0 = blockIdx.x * GBM;
  const int col0 = blockIdx.y * GBN;
  const unsigned gth = (blockIdx.y * gridDim.x + blockIdx.x) * 256 + tid;

  const int sr = tid >> 2;          // staging row 0..63
  const int sc = (tid & 3) * 8;     // staging k-col 0,8,16,24

  const short* gA  = imgb  + (size_t)(row0 + sr) * DIM + sc;
  const short* gB0 = protb + (size_t)(col0 + sr) * DIM + sc;
  const short* gB1 = protb + (size_t)(col0 + 64 + sr) * DIM + sc;

  s16x8 ra  = *(const s16x8*)gA;
  s16x8 rb0 = *(const s16x8*)gB0;
  s16x8 rb1 = *(const s16x8*)gB1;

  f32x4 acc[2][4];
#pragma unroll
  for (int m = 0; m < 2; ++m)
#pragma unroll
    for (int n = 0; n < 4; ++n) acc[m][n] = (f32x4)0.f;

  const int kg = lane >> 4;   // k-group 0..3
  const int fr = lane & 15;   // fragment row/col

  for (int kt = 0; kt < DIM / GBK; ++kt) {
    *(s16x8*)&Al[sr * ALD + sc]        = ra;
    *(s16x8*)&Bl[sr * ALD + sc]        = rb0;
    *(s16x8*)&Bl[(64 + sr) * ALD + sc] = rb1;
    __syncthreads();

    if (kt + 1 < DIM / GBK) {
      const int k0 = (kt + 1) * GBK;
      ra  = *(const s16x8*)(gA + k0);
      rb0 = *(const s16x8*)(gB0 + k0);
      rb1 = *(const s16x8*)(gB1 + k0);
    }

    s16x8 af[2], bf[4];
#pragma unroll
    for (int m = 0; m < 2; ++m)
      af[m] = *(const s16x8*)&Al[(wr * 32 + m * 16 + fr) * ALD + kg * 8];
#pragma unroll
    for (int n = 0; n < 4; ++n)
      bf[n] = *(const s16x8*)&Bl[(wc * 64 + n * 16 + fr) * ALD + kg * 8];
#pragma unroll
    for (int m = 0; m < 2; ++m)
#pragma unroll
      for (int n = 0; n < 4; ++n)
        acc[m][n] = __builtin_amdgcn_mfma_f32_16x16x32_bf16(
            af[m], bf[n], acc[m][n], 0, 0, 0);
    __syncthreads();
  }

  // epilogue: C/D layout (m89/m91): col = lane&15, row = (lane>>4)*4 + reg
#pragma unroll
  for (int m = 0; m < 2; ++m)
#pragma unroll
    for (int n = 0; n < 4; ++n) {
      const int r = row0 + wr * 32 + m * 16 + (lane >> 4) * 4;
      const int c = col0 + wc * 64 + n * 16 + fr;
#pragma unroll
      for (int reg = 0; reg < 4; ++reg)
        prob[(size_t)(r + reg) * PROB_LD + c] = acc[m][n][reg];
    }

  // post-loop zero share: no barrier after this -> fully async drain
  zero_share(zhi, ZS_GEMM, ZQ_GEMM, gth, 512 * 256);
}

// ---------------------------------------------------------------------------
// Kernel 2: per-row top-16 candidates (one wave per row; no barriers at all).
// ---------------------------------------------------------------------------
__global__ __launch_bounds__(256) void k_topk(
    const float* __restrict__ prob, int* __restrict__ cand,
    f32x4* __restrict__ zhi)
{
  __shared__ float srow[4][PROB_LD];
  const int tid  = threadIdx.x;
  const int wave = tid >> 6, lane = tid & 63;
  const int row  = blockIdx.x * 4 + wave;

  const float* p = prob + (size_t)row * PROB_LD;
#pragma unroll
  for (int i = 0; i < PROB_LD / 64; ++i) {
    const int j = lane + i * 64;
    srow[wave][j] = (j < NPROTO) ? p[j] : -FLT_MAX;
  }

  for (int kk = 0; kk < KCAND; ++kk) {
    float bv = -FLT_MAX;
    int   bi = 0x7fffffff;
#pragma unroll
    for (int i = 0; i < PROB_LD / 64; ++i) {
      const int j = lane + i * 64;
      float v = srow[wave][j];
      if (v > bv || (v == bv && j < bi)) { bv = v; bi = j; }
    }
#pragma unroll
    for (int off = 32; off; off >>= 1) {
      float ov = __shfl_down(bv, off);
      int   oi = __shfl_down(bi, off);
      if (ov > bv || (ov == bv && oi < bi)) { bv = ov; bi = oi; }
    }
    bi = __shfl(bi, 0);
    if (lane == 0) cand[(size_t)row * KCAND + kk] = bi;
    srow[wave][bi] = -FLT_MAX;
  }

  zero_share(zhi, ZS_TOPK, ZQ_TOPK, blockIdx.x * 256 + tid, 1024 * 256);
}

// ---------------------------------------------------------------------------
// Kernel 3: exact f32 rescore of the 16 candidates -> top-10 set; zeroes
// zlo (prob + bf16 scratch, dead after topk) + its zhi share.
// ---------------------------------------------------------------------------
__global__ __launch_bounds__(256) void k_rescore(
    const float* __restrict__ img, const float* __restrict__ proto,
    const int* __restrict__ cand, int* __restrict__ topk,
    f32x4* __restrict__ zlo, f32x4* __restrict__ zhi)
{
  const int tid  = threadIdx.x;
  const int wave = tid >> 6, lane = tid & 63;
  const int row  = blockIdx.x * 4 + wave;

  const float4* a4 = reinterpret_cast<const float4*>(img + (size_t)row * DIM);
  const float4 a0 = a4[lane], a1 = a4[64 + lane];

  int   ci[KCAND];
  float dv[KCAND];
#pragma unroll
  for (int j = 0; j < KCAND; ++j) {
    ci[j] = cand[(size_t)row * KCAND + j];
    const float4* p4 = reinterpret_cast<const float4*>(proto + (size_t)ci[j] * DIM);
    const float4 b0 = p4[lane], b1 = p4[64 + lane];
    float s = 0.f;
    s = fmaf(a0.x, b0.x, s); s = fmaf(a0.y, b0.y, s);
    s = fmaf(a0.z, b0.z, s); s = fmaf(a0.w, b0.w, s);
    s = fmaf(a1.x, b1.x, s); s = fmaf(a1.y, b1.y, s);
    s = fmaf(a1.z, b1.z, s); s = fmaf(a1.w, b1.w, s);
#pragma unroll
    for (int off = 32; off; off >>= 1) s += __shfl_xor(s, off);
    dv[j] = s;
  }

  unsigned picked = 0;
  for (int kk = 0; kk < KSEL; ++kk) {
    float bv = -FLT_MAX;
    int   bj = 0;
#pragma unroll
    for (int j = 0; j < KCAND; ++j)
      if (!((picked >> j) & 1u) && dv[j] > bv) { bv = dv[j]; bj = j; }
    picked |= 1u << bj;
    if (lane == kk) topk[(size_t)row * KSEL + kk] = ci[bj];
  }

  const unsigned gth = blockIdx.x * 256 + tid;     // 0..262143
  zero_share(zlo, 0, ZLO_N4, gth, 1024 * 256);
  zero_share(zhi, ZS_RESC, ZQ_RESC, gth, 1024 * 256);
}

// ---------------------------------------------------------------------------
// Kernel 4: invert (row -> protos) into per-proto row buckets + zero share.
// Grid enlarged to 2048 blocks so the zero share isn't thread-starved.
// ---------------------------------------------------------------------------
__global__ __launch_bounds__(256) void k_build(
    const int* __restrict__ topk, int* __restrict__ counts,
    int* __restrict__ buckets, f32x4* __restrict__ zhi)
{
  const int g = blockIdx.x * 256 + threadIdx.x;
  if (g < NPAIRS) {
    const int p   = topk[g];
    const int row = g / KSEL;
    const int pos = atomicAdd(&counts[p], 1);
    if (pos < CAP) buckets[p * CAP + pos] = row;
  }
  zero_share(zhi, ZS_BUILD, ZQ_BUILD, (unsigned)g, 2048 * 256);
}

// ---------------------------------------------------------------------------
// Kernel 5: one block per proto; stage + normalize its 10 text rows in LDS,
// then compute the 10 dots for each bucketed image row.
// ---------------------------------------------------------------------------
__global__ __launch_bounds__(256) void k_compute(
    const float* __restrict__ img, const float* __restrict__ text,
    const int* __restrict__ counts, const int* __restrict__ buckets,
    const float* __restrict__ logit_scale, float* __restrict__ out)
{
  __shared__ float stext[KSEL * DIM];
  __shared__ float sfac[KSEL];

  const int p    = blockIdx.x;
  const int tid  = threadIdx.x;
  const int wave = tid >> 6, lane = tid & 63;

  {
    const float4* src = reinterpret_cast<const float4*>(text + (size_t)p * KSEL * DIM);
    float4* dst = reinterpret_cast<float4*>(stext);
#pragma unroll
    for (int i = 0; i < 5; ++i) dst[tid + i * 256] = src[tid + i * 256];
  }
  __syncthreads();

  const float scale = expf(logit_scale[0]);
#pragma unroll
  for (int j = wave; j < KSEL; j += 4) {
    const float4* t4 = reinterpret_cast<const float4*>(stext + j * DIM);
    float4 v0 = t4[lane], v1 = t4[64 + lane];
    float s = 0.f;
    s = fmaf(v0.x, v0.x, s); s = fmaf(v0.y, v0.y, s);
    s = fmaf(v0.z, v0.z, s); s = fmaf(v0.w, v0.w, s);
    s = fmaf(v1.x, v1.x, s); s = fmaf(v1.y, v1.y, s);
    s = fmaf(v1.z, v1.z, s); s = fmaf(v1.w, v1.w, s);
#pragma unroll
    for (int off = 32; off; off >>= 1) s += __shfl_down(s, off);
    if (lane == 0) sfac[j] = scale / sqrtf(s);
  }
  __syncthreads();

  {
    float4* st4 = reinterpret_cast<float4*>(stext);
#pragma unroll
    for (int i = 0; i < 5; ++i) {
      const int idx = tid + i * 256;
      const float f = sfac[idx >> 7];
      float4 v = st4[idx];
      v.x *= f; v.y *= f; v.z *= f; v.w *= f;
      st4[idx] = v;
    }
  }
  __syncthreads();

  const int n = min(counts[p], CAP);
  const float4* st4 = reinterpret_cast<const float4*>(stext);

  for (int i = wave; i < n; i += 4) {
    const int row = buckets[p * CAP + i];
    const float4* a4 = reinterpret_cast<const float4*>(img + (size_t)row * DIM);
    const float4 a0 = a4[lane], a1 = a4[64 + lane];

    float acc[KSEL];
#pragma unroll
    for (int j = 0; j < KSEL; ++j) {
      const float4 b0 = st4[j * 128 + lane];
      const float4 b1 = st4[j * 128 + 64 + lane];
      float s = 0.f;
      s = fmaf(a0.x, b0.x, s); s = fmaf(a0.y, b0.y, s);
      s = fmaf(a0.z, b0.z, s); s = fmaf(a0.w, b0.w, s);
      s = fmaf(a1.x, b1.x, s); s = fmaf(a1.y, b1.y, s);
      s = fmaf(a1.z, b1.z, s); s = fmaf(a1.w, b1.w, s);
      acc[j] = s;
    }
#pragma unroll
    for (int j = 0; j < KSEL; ++j) {
#pragma unroll
      for (int off = 32; off; off >>= 1)
        acc[j] += __shfl_xor(acc[j], off);
    }
    float v = acc[0];
#pragma unroll
    for (int j = 1; j < KSEL; ++j) if (lane == j) v = acc[j];
    if (lane < KSEL)
      out[(size_t)row * NCLASSES + p * KSEL + lane] = v;
  }
}

// ---------------------------------------------------------------------------
extern "C" void kernel_launch(void* const* d_in, const int* in_sizes, int n_in,
                              void* d_out, int out_size, void* d_ws, size_t ws_size,
                              hipStream_t stream) {
  const float* img    = (const float*)d_in[0];
  const float* proto  = (const float*)d_in[1];
  const float* text   = (const float*)d_in[2];
  const float* lscale = (const float*)d_in[3];

  float*  prob  = (float*)d_out;
  short*  imgb  = (short*)((char*)d_out + IMGB_OFF);
  short*  protb = (short*)((char*)d_out + PROTB_OFF);
  f32x4*  zlo   = (f32x4*)d_out;
  f32x4*  zhi   = (f32x4*)((char*)d_out + ZLO_BYTES);
  float*  out   = (float*)d_out;

  // ws layout (~1.45 MB)
  int* cand    = (int*)d_ws;                                   // 4096*16*4
  int* topk    = (int*)((char*)d_ws + 262144);                 // 4096*10*4
  int* counts  = (int*)((char*)d_ws + 262144 + 163840);        // 1000*4
  int* buckets = (int*)((char*)d_ws + 262144 + 163840 + 4096); // 1000*256*4

  k_convert<<<1280, 256, 0, stream>>>(img, proto, imgb, protb, counts, zhi);
  k_gemm_mfma<<<dim3(B_ROWS / GBM, NPROTO_P / GBN), 256, 0, stream>>>(
      imgb, protb, prob, zhi);
  k_topk<<<B_ROWS / 4, 256, 0, stream>>>(prob, cand, zhi);
  k_rescore<<<B_ROWS / 4, 256, 0, stream>>>(img, proto, cand, topk, zlo, zhi);
  k_build<<<2048, 256, 0, stream>>>(topk, counts, buckets, zhi);
  k_compute<<<NPROTO, 256, 0, stream>>>(img, text, counts, buckets, lscale, out);
}

// Round 8
// 122.499 us; speedup vs baseline: 4.9966x; 1.1100x over previous
//
#include <hip/hip_runtime.h>
#include <cfloat>
#include <math.h>

// Problem constants (fixed by the reference)
#define B_ROWS   4096
#define DIM      512
#define NPROTO   1000
#define NCLASSES 10000
#define KSEL     10
#define KCAND    16                // approx candidates rescored in f32
#define CAP      256               // bucket capacity (avg 41)
#define PROB_LD  1024

// d_out layout: prob f32 4096x1024 at [0, PROB_BYTES). k_select self-zeroes
// each prob row after consuming it; zhi = [PROB_BYTES, OUT) is zeroed in
// shares by k_gemm (post-loop) and k_select. All zero stores are
// post-compute NT stores with no barrier after (R6 lesson: a barrier forces
// vmcnt(0) drain and serializes).
#define PROB_BYTES 16777216u
#define OUT_BYTES  163840000u
#define ZHI_N4     ((OUT_BYTES - PROB_BYTES) / 16)   // 9191424 f32x4
#define ZQ1        5000000u                          // 80 MB zeroed by gemm
#define ZS1        0u
#define ZQ2        (ZHI_N4 - ZQ1)                    // ~67 MB zeroed by select
#define ZS2        ZQ1

// MFMA GEMM tiling
#define GBM 64
#define GBN 128
#define GBK 32
#define ALD 40                     // padded LDS row stride (bf16 elems)

typedef short s16x8 __attribute__((ext_vector_type(8)));
typedef float f32x4 __attribute__((ext_vector_type(4)));

static __device__ __forceinline__ unsigned short f2bf(float f) {
  unsigned int x = __float_as_uint(f);
  return (unsigned short)((x + 0x7fffu + ((x >> 16) & 1u)) >> 16);  // RNE
}

static __device__ __forceinline__ s16x8 cvt8(float4 a, float4 b) {
  s16x8 r;
  r[0]=f2bf(a.x); r[1]=f2bf(a.y); r[2]=f2bf(a.z); r[3]=f2bf(a.w);
  r[4]=f2bf(b.x); r[5]=f2bf(b.y); r[6]=f2bf(b.z); r[7]=f2bf(b.w);
  return r;
}

static __device__ __forceinline__ void zero_share(
    f32x4* __restrict__ zhi, unsigned start, unsigned count,
    unsigned gth, unsigned nthreads)
{
  const f32x4 z4 = (f32x4)0.f;
  for (unsigned i = start + gth; i < start + count; i += nthreads)
    __builtin_nontemporal_store(z4, zhi + i);
}

// ---------------------------------------------------------------------------
// Kernel 1: prob = bf16(img) @ bf16(proto).T via 16x16x32 MFMA, converting
// f32->bf16 inline at the LDS-store site. Block (0,0) zeroes counts; every
// block writes its zhi zero share post-loop (async drain, no barrier after).
// B rows >= NPROTO are clamped (their prob cols are masked in k_select).
// ---------------------------------------------------------------------------
__global__ __launch_bounds__(256) void k_gemm(
    const float* __restrict__ img, const float* __restrict__ proto,
    float* __restrict__ prob, f32x4* __restrict__ zhi,
    int* __restrict__ counts)
{
  __shared__ short Al[GBM * ALD];   // 5 KB
  __shared__ short Bl[GBN * ALD];   // 10 KB

  const int tid  = threadIdx.x;
  const int lane = tid & 63, wave = tid >> 6;
  const int wr = wave >> 1, wc = wave & 1;
  const int row0 = blockIdx.x * GBM;
  const int col0 = blockIdx.y * GBN;
  const unsigned gth = (blockIdx.y * gridDim.x + blockIdx.x) * 256 + tid;

  const int sr = tid >> 2;          // staging row 0..63
  const int sc = (tid & 3) * 8;     // staging k-col 0,8,16,24

  int pa = col0 + sr;      if (pa > NPROTO - 1) pa = NPROTO - 1;
  int pb = col0 + 64 + sr; if (pb > NPROTO - 1) pb = NPROTO - 1;
  const float* gA  = img   + (size_t)(row0 + sr) * DIM + sc;
  const float* gB0 = proto + (size_t)pa * DIM + sc;
  const float* gB1 = proto + (size_t)pb * DIM + sc;

  float4 ra0  = *(const float4*)(gA);      float4 ra1  = *(const float4*)(gA + 4);
  float4 rb00 = *(const float4*)(gB0);     float4 rb01 = *(const float4*)(gB0 + 4);
  float4 rb10 = *(const float4*)(gB1);     float4 rb11 = *(const float4*)(gB1 + 4);

  f32x4 acc[2][4];
#pragma unroll
  for (int m = 0; m < 2; ++m)
#pragma unroll
    for (int n = 0; n < 4; ++n) acc[m][n] = (f32x4)0.f;

  const int kg = lane >> 4;   // k-group 0..3
  const int fr = lane & 15;   // fragment row/col

  for (int kt = 0; kt < DIM / GBK; ++kt) {
    *(s16x8*)&Al[sr * ALD + sc]        = cvt8(ra0, ra1);
    *(s16x8*)&Bl[sr * ALD + sc]        = cvt8(rb00, rb01);
    *(s16x8*)&Bl[(64 + sr) * ALD + sc] = cvt8(rb10, rb11);
    __syncthreads();

    if (kt + 1 < DIM / GBK) {
      const int k0 = (kt + 1) * GBK;
      ra0  = *(const float4*)(gA + k0);   ra1  = *(const float4*)(gA + k0 + 4);
      rb00 = *(const float4*)(gB0 + k0);  rb01 = *(const float4*)(gB0 + k0 + 4);
      rb10 = *(const float4*)(gB1 + k0);  rb11 = *(const float4*)(gB1 + k0 + 4);
    }

    s16x8 af[2], bf[4];
#pragma unroll
    for (int m = 0; m < 2; ++m)
      af[m] = *(const s16x8*)&Al[(wr * 32 + m * 16 + fr) * ALD + kg * 8];
#pragma unroll
    for (int n = 0; n < 4; ++n)
      bf[n] = *(const s16x8*)&Bl[(wc * 64 + n * 16 + fr) * ALD + kg * 8];
#pragma unroll
    for (int m = 0; m < 2; ++m)
#pragma unroll
      for (int n = 0; n < 4; ++n)
        acc[m][n] = __builtin_amdgcn_mfma_f32_16x16x32_bf16(
            af[m], bf[n], acc[m][n], 0, 0, 0);
    __syncthreads();
  }

  // epilogue: C/D layout (m89/m91): col = lane&15, row = (lane>>4)*4 + reg
#pragma unroll
  for (int m = 0; m < 2; ++m)
#pragma unroll
    for (int n = 0; n < 4; ++n) {
      const int r = row0 + wr * 32 + m * 16 + (lane >> 4) * 4;
      const int c = col0 + wc * 64 + n * 16 + fr;
#pragma unroll
      for (int reg = 0; reg < 4; ++reg)
        prob[(size_t)(r + reg) * PROB_LD + c] = acc[m][n][reg];
    }

  if (blockIdx.x == 0 && blockIdx.y == 0)
    for (int i = tid; i < NPROTO; i += 256) counts[i] = 0;

  // post-loop zero share: no barrier after -> fully async drain
  zero_share(zhi, ZS1, ZQ1, gth, 512 * 256);
}

// ---------------------------------------------------------------------------
// Kernel 2: fused top-16 -> f32 rescore -> top-10 pick -> bucket build.
// One wave per row. The wave self-zeroes the prob row it consumed (race-free)
// and writes its zhi zero share.
// ---------------------------------------------------------------------------
__global__ __launch_bounds__(256) void k_select(
    float* __restrict__ prob, const float* __restrict__ img,
    const float* __restrict__ proto, int* __restrict__ counts,
    int* __restrict__ buckets, f32x4* __restrict__ zhi)
{
  __shared__ float srow[4][PROB_LD];   // 16 KB
  const int tid  = threadIdx.x;
  const int wave = tid >> 6, lane = tid & 63;
  const int row  = blockIdx.x * 4 + wave;

  const float* p = prob + (size_t)row * PROB_LD;
#pragma unroll
  for (int i = 0; i < PROB_LD / 64; ++i) {
    const int j = lane + i * 64;
    srow[wave][j] = (j < NPROTO) ? p[j] : -FLT_MAX;
  }

  // top-16 candidates: iterative argmax, lowest-index tie-break (jax set)
  int ci[KCAND];
  for (int kk = 0; kk < KCAND; ++kk) {
    float bv = -FLT_MAX;
    int   bi = 0x7fffffff;
#pragma unroll
    for (int i = 0; i < PROB_LD / 64; ++i) {
      const int j = lane + i * 64;
      float v = srow[wave][j];
      if (v > bv || (v == bv && j < bi)) { bv = v; bi = j; }
    }
#pragma unroll
    for (int off = 32; off; off >>= 1) {
      float ov = __shfl_down(bv, off);
      int   oi = __shfl_down(bi, off);
      if (ov > bv || (ov == bv && oi < bi)) { bv = ov; bi = oi; }
    }
    bi = __shfl(bi, 0);
    ci[kk] = bi;
    srow[wave][bi] = -FLT_MAX;   // all lanes, same addr/value
  }

  // self-zero the consumed prob row (it is dead from here on)
  {
    const f32x4 z4 = (f32x4)0.f;
    f32x4* prow = reinterpret_cast<f32x4*>(prob + (size_t)row * PROB_LD);
#pragma unroll
    for (int i = 0; i < 4; ++i)
      __builtin_nontemporal_store(z4, prow + lane + i * 64);
  }

  // exact f32 rescore of the 16 candidates
  const float4* a4 = reinterpret_cast<const float4*>(img + (size_t)row * DIM);
  const float4 a0 = a4[lane], a1 = a4[64 + lane];
  float dv[KCAND];
#pragma unroll
  for (int j = 0; j < KCAND; ++j) {
    const float4* p4 = reinterpret_cast<const float4*>(proto + (size_t)ci[j] * DIM);
    const float4 b0 = p4[lane], b1 = p4[64 + lane];
    float s = 0.f;
    s = fmaf(a0.x, b0.x, s); s = fmaf(a0.y, b0.y, s);
    s = fmaf(a0.z, b0.z, s); s = fmaf(a0.w, b0.w, s);
    s = fmaf(a1.x, b1.x, s); s = fmaf(a1.y, b1.y, s);
    s = fmaf(a1.z, b1.z, s); s = fmaf(a1.w, b1.w, s);
#pragma unroll
    for (int off = 32; off; off >>= 1) s += __shfl_xor(s, off);
    dv[j] = s;
  }

  // top-10 pick (uniform across lanes) + bucket build (lane kk does pick kk)
  unsigned picked = 0;
  for (int kk = 0; kk < KSEL; ++kk) {
    float bv = -FLT_MAX;
    int   bj = 0;
#pragma unroll
    for (int j = 0; j < KCAND; ++j)
      if (!((picked >> j) & 1u) && dv[j] > bv) { bv = dv[j]; bj = j; }
    picked |= 1u << bj;
    if (lane == kk) {
      const int pp  = ci[bj];
      const int pos = atomicAdd(&counts[pp], 1);
      if (pos < CAP) buckets[pp * CAP + pos] = row;
    }
  }

  zero_share(zhi, ZS2, ZQ2, blockIdx.x * 256 + tid, 1024 * 256);
}

// ---------------------------------------------------------------------------
// Kernel 3: one block per proto; stage + normalize its 10 text rows in LDS,
// then compute the 10 dots for each bucketed image row.
// ---------------------------------------------------------------------------
__global__ __launch_bounds__(256) void k_compute(
    const float* __restrict__ img, const float* __restrict__ text,
    const int* __restrict__ counts, const int* __restrict__ buckets,
    const float* __restrict__ logit_scale, float* __restrict__ out)
{
  __shared__ float stext[KSEL * DIM];
  __shared__ float sfac[KSEL];

  const int p    = blockIdx.x;
  const int tid  = threadIdx.x;
  const int wave = tid >> 6, lane = tid & 63;

  {
    const float4* src = reinterpret_cast<const float4*>(text + (size_t)p * KSEL * DIM);
    float4* dst = reinterpret_cast<float4*>(stext);
#pragma unroll
    for (int i = 0; i < 5; ++i) dst[tid + i * 256] = src[tid + i * 256];
  }
  __syncthreads();

  const float scale = expf(logit_scale[0]);
#pragma unroll
  for (int j = wave; j < KSEL; j += 4) {
    const float4* t4 = reinterpret_cast<const float4*>(stext + j * DIM);
    float4 v0 = t4[lane], v1 = t4[64 + lane];
    float s = 0.f;
    s = fmaf(v0.x, v0.x, s); s = fmaf(v0.y, v0.y, s);
    s = fmaf(v0.z, v0.z, s); s = fmaf(v0.w, v0.w, s);
    s = fmaf(v1.x, v1.x, s); s = fmaf(v1.y, v1.y, s);
    s = fmaf(v1.z, v1.z, s); s = fmaf(v1.w, v1.w, s);
#pragma unroll
    for (int off = 32; off; off >>= 1) s += __shfl_down(s, off);
    if (lane == 0) sfac[j] = scale / sqrtf(s);
  }
  __syncthreads();

  {
    float4* st4 = reinterpret_cast<float4*>(stext);
#pragma unroll
    for (int i = 0; i < 5; ++i) {
      const int idx = tid + i * 256;
      const float f = sfac[idx >> 7];
      float4 v = st4[idx];
      v.x *= f; v.y *= f; v.z *= f; v.w *= f;
      st4[idx] = v;
    }
  }
  __syncthreads();

  const int n = min(counts[p], CAP);
  const float4* st4 = reinterpret_cast<const float4*>(stext);

  for (int i = wave; i < n; i += 4) {
    const int row = buckets[p * CAP + i];
    const float4* a4 = reinterpret_cast<const float4*>(img + (size_t)row * DIM);
    const float4 a0 = a4[lane], a1 = a4[64 + lane];

    float acc[KSEL];
#pragma unroll
    for (int j = 0; j < KSEL; ++j) {
      const float4 b0 = st4[j * 128 + lane];
      const float4 b1 = st4[j * 128 + 64 + lane];
      float s = 0.f;
      s = fmaf(a0.x, b0.x, s); s = fmaf(a0.y, b0.y, s);
      s = fmaf(a0.z, b0.z, s); s = fmaf(a0.w, b0.w, s);
      s = fmaf(a1.x, b1.x, s); s = fmaf(a1.y, b1.y, s);
      s = fmaf(a1.z, b1.z, s); s = fmaf(a1.w, b1.w, s);
      acc[j] = s;
    }
#pragma unroll
    for (int j = 0; j < KSEL; ++j) {
#pragma unroll
      for (int off = 32; off; off >>= 1)
        acc[j] += __shfl_xor(acc[j], off);
    }
    float v = acc[0];
#pragma unroll
    for (int j = 1; j < KSEL; ++j) if (lane == j) v = acc[j];
    if (lane < KSEL)
      out[(size_t)row * NCLASSES + p * KSEL + lane] = v;
  }
}

// ---------------------------------------------------------------------------
extern "C" void kernel_launch(void* const* d_in, const int* in_sizes, int n_in,
                              void* d_out, int out_size, void* d_ws, size_t ws_size,
                              hipStream_t stream) {
  const float* img    = (const float*)d_in[0];
  const float* proto  = (const float*)d_in[1];
  const float* text   = (const float*)d_in[2];
  const float* lscale = (const float*)d_in[3];

  float*  prob = (float*)d_out;
  f32x4*  zhi  = (f32x4*)((char*)d_out + PROB_BYTES);
  float*  out  = (float*)d_out;

  // ws layout (~1.03 MB)
  int* counts  = (int*)d_ws;                      // 1000*4 (pad to 4096)
  int* buckets = (int*)((char*)d_ws + 4096);      // 1000*256*4

  k_gemm<<<dim3(B_ROWS / GBM, 1024 / GBN), 256, 0, stream>>>(
      img, proto, prob, zhi, counts);
  k_select<<<B_ROWS / 4, 256, 0, stream>>>(prob, img, proto, counts, buckets, zhi);
  k_compute<<<NPROTO, 256, 0, stream>>>(img, text, counts, buckets, lscale, out);
}

// Round 9
// 110.870 us; speedup vs baseline: 5.5207x; 1.1049x over previous
//
#include <hip/hip_runtime.h>
#include <cfloat>
#include <math.h>

// Problem constants (fixed by the reference)
#define B_ROWS   4096
#define DIM      512
#define NPROTO   1000
#define NCLASSES 10000
#define KSEL     10
#define KCAND    12                // approx candidates rescored in f32
#define CAP      256               // bucket capacity (avg 41)
#define PROB_LD  1024

// d_out layout: prob f16 4096x1024 at [0, PROB_BYTES). k_select self-zeroes
// each prob row after consuming it; zhi = [PROB_BYTES, OUT) is zeroed in
// shares by k_gemm (post-loop) and k_select, always as POST-compute NT
// stores with no barrier after (R6 lesson: barrier forces vmcnt(0) drain).
#define PROB_BYTES 8388608u
#define OUT_BYTES  163840000u
#define ZHI_N4     ((OUT_BYTES - PROB_BYTES) / 16)   // 9715712 f32x4
#define ZQ1        6000000u                          // 96 MB zeroed by gemm
#define ZS1        0u
#define ZQ2        (ZHI_N4 - ZQ1)                    // ~59.5 MB by select
#define ZS2        ZQ1

// MFMA GEMM tiling
#define GBM 64
#define GBN 128
#define GBK 32
#define ALD 40                     // padded LDS row stride (bf16 elems)

typedef short s16x8 __attribute__((ext_vector_type(8)));
typedef float f32x4 __attribute__((ext_vector_type(4)));

static __device__ __forceinline__ unsigned short f2bf(float f) {
  unsigned int x = __float_as_uint(f);
  return (unsigned short)((x + 0x7fffu + ((x >> 16) & 1u)) >> 16);  // RNE
}
static __device__ __forceinline__ s16x8 cvt8(float4 a, float4 b) {
  s16x8 r;
  r[0]=f2bf(a.x); r[1]=f2bf(a.y); r[2]=f2bf(a.z); r[3]=f2bf(a.w);
  r[4]=f2bf(b.x); r[5]=f2bf(b.y); r[6]=f2bf(b.z); r[7]=f2bf(b.w);
  return r;
}
static __device__ __forceinline__ unsigned short f2h(float f) {
  _Float16 h = (_Float16)f;
  return __builtin_bit_cast(unsigned short, h);
}
static __device__ __forceinline__ float h2f(unsigned short u) {
  _Float16 h = __builtin_bit_cast(_Float16, u);
  return (float)h;
}

static __device__ __forceinline__ void zero_share(
    f32x4* __restrict__ zhi, unsigned start, unsigned count,
    unsigned gth, unsigned nthreads)
{
  const f32x4 z4 = (f32x4)0.f;
  for (unsigned i = start + gth; i < start + count; i += nthreads)
    __builtin_nontemporal_store(z4, zhi + i);
}

// ---------------------------------------------------------------------------
// Kernel 1: prob(f16) = bf16(img) @ bf16(proto).T via 16x16x32 MFMA,
// f32->bf16 inline at the LDS-store site. Block (0,0) zeroes counts; every
// block writes its zhi zero share post-loop (async drain, no barrier after).
// ---------------------------------------------------------------------------
__global__ __launch_bounds__(256) void k_gemm(
    const float* __restrict__ img, const float* __restrict__ proto,
    unsigned short* __restrict__ prob, f32x4* __restrict__ zhi,
    int* __restrict__ counts)
{
  __shared__ short Al[GBM * ALD];   // 5 KB
  __shared__ short Bl[GBN * ALD];   // 10 KB

  const int tid  = threadIdx.x;
  const int lane = tid & 63, wave = tid >> 6;
  const int wr = wave >> 1, wc = wave & 1;
  const int row0 = blockIdx.x * GBM;
  const int col0 = blockIdx.y * GBN;
  const unsigned gth = (blockIdx.y * gridDim.x + blockIdx.x) * 256 + tid;

  const int sr = tid >> 2;          // staging row 0..63
  const int sc = (tid & 3) * 8;     // staging k-col 0,8,16,24

  int pa = col0 + sr;      if (pa > NPROTO - 1) pa = NPROTO - 1;
  int pb = col0 + 64 + sr; if (pb > NPROTO - 1) pb = NPROTO - 1;
  const float* gA  = img   + (size_t)(row0 + sr) * DIM + sc;
  const float* gB0 = proto + (size_t)pa * DIM + sc;
  const float* gB1 = proto + (size_t)pb * DIM + sc;

  float4 ra0  = *(const float4*)(gA);      float4 ra1  = *(const float4*)(gA + 4);
  float4 rb00 = *(const float4*)(gB0);     float4 rb01 = *(const float4*)(gB0 + 4);
  float4 rb10 = *(const float4*)(gB1);     float4 rb11 = *(const float4*)(gB1 + 4);

  f32x4 acc[2][4];
#pragma unroll
  for (int m = 0; m < 2; ++m)
#pragma unroll
    for (int n = 0; n < 4; ++n) acc[m][n] = (f32x4)0.f;

  const int kg = lane >> 4;   // k-group 0..3
  const int fr = lane & 15;   // fragment row/col

  for (int kt = 0; kt < DIM / GBK; ++kt) {
    *(s16x8*)&Al[sr * ALD + sc]        = cvt8(ra0, ra1);
    *(s16x8*)&Bl[sr * ALD + sc]        = cvt8(rb00, rb01);
    *(s16x8*)&Bl[(64 + sr) * ALD + sc] = cvt8(rb10, rb11);
    __syncthreads();

    if (kt + 1 < DIM / GBK) {
      const int k0 = (kt + 1) * GBK;
      ra0  = *(const float4*)(gA + k0);   ra1  = *(const float4*)(gA + k0 + 4);
      rb00 = *(const float4*)(gB0 + k0);  rb01 = *(const float4*)(gB0 + k0 + 4);
      rb10 = *(const float4*)(gB1 + k0);  rb11 = *(const float4*)(gB1 + k0 + 4);
    }

    s16x8 af[2], bf[4];
#pragma unroll
    for (int m = 0; m < 2; ++m)
      af[m] = *(const s16x8*)&Al[(wr * 32 + m * 16 + fr) * ALD + kg * 8];
#pragma unroll
    for (int n = 0; n < 4; ++n)
      bf[n] = *(const s16x8*)&Bl[(wc * 64 + n * 16 + fr) * ALD + kg * 8];
#pragma unroll
    for (int m = 0; m < 2; ++m)
#pragma unroll
      for (int n = 0; n < 4; ++n)
        acc[m][n] = __builtin_amdgcn_mfma_f32_16x16x32_bf16(
            af[m], bf[n], acc[m][n], 0, 0, 0);
    __syncthreads();
  }

  // epilogue: C/D layout (m89/m91): col = lane&15, row = (lane>>4)*4 + reg
#pragma unroll
  for (int m = 0; m < 2; ++m)
#pragma unroll
    for (int n = 0; n < 4; ++n) {
      const int r = row0 + wr * 32 + m * 16 + (lane >> 4) * 4;
      const int c = col0 + wc * 64 + n * 16 + fr;
#pragma unroll
      for (int reg = 0; reg < 4; ++reg)
        prob[(size_t)(r + reg) * PROB_LD + c] = f2h(acc[m][n][reg]);
    }

  if (blockIdx.x == 0 && blockIdx.y == 0)
    for (int i = tid; i < NPROTO; i += 256) counts[i] = 0;

  // post-loop zero share: no barrier after -> fully async drain
  zero_share(zhi, ZS1, ZQ1, gth, 512 * 256);
}

// ---------------------------------------------------------------------------
// Kernel 2: fused top-12 -> f32 rescore -> top-10 pick -> bucket build.
// One wave per row. The wave self-zeroes the f16 prob row it consumed.
// ---------------------------------------------------------------------------
__global__ __launch_bounds__(256) void k_select(
    unsigned short* __restrict__ prob, const float* __restrict__ img,
    const float* __restrict__ proto, int* __restrict__ counts,
    int* __restrict__ buckets, f32x4* __restrict__ zhi)
{
  __shared__ float srow[4][PROB_LD];   // 16 KB
  const int tid  = threadIdx.x;
  const int wave = tid >> 6, lane = tid & 63;
  const int row  = blockIdx.x * 4 + wave;

  // load f16 row as u32 pairs, unpack to f32 LDS (mask cols >= NPROTO)
  {
    const unsigned* pu = reinterpret_cast<const unsigned*>(
        prob + (size_t)row * PROB_LD);
#pragma unroll
    for (int i = 0; i < 8; ++i) {
      const int idx = lane + i * 64;          // u32 index, cols 2idx,2idx+1
      const unsigned u = pu[idx];
      const int c0 = idx * 2;
      srow[wave][c0]     = (c0     < NPROTO) ? h2f((unsigned short)(u & 0xffff)) : -FLT_MAX;
      srow[wave][c0 + 1] = (c0 + 1 < NPROTO) ? h2f((unsigned short)(u >> 16))    : -FLT_MAX;
    }
  }

  // top-12 candidates: iterative argmax, lowest-index tie-break
  int ci[KCAND];
  for (int kk = 0; kk < KCAND; ++kk) {
    float bv = -FLT_MAX;
    int   bi = 0x7fffffff;
#pragma unroll
    for (int i = 0; i < PROB_LD / 64; ++i) {
      const int j = lane + i * 64;
      float v = srow[wave][j];
      if (v > bv || (v == bv && j < bi)) { bv = v; bi = j; }
    }
#pragma unroll
    for (int off = 32; off; off >>= 1) {
      float ov = __shfl_down(bv, off);
      int   oi = __shfl_down(bi, off);
      if (ov > bv || (ov == bv && oi < bi)) { bv = ov; bi = oi; }
    }
    bi = __shfl(bi, 0);
    ci[kk] = bi;
    srow[wave][bi] = -FLT_MAX;   // all lanes, same addr/value
  }

  // self-zero the consumed f16 prob row (2 KB = 128 f32x4)
  {
    const f32x4 z4 = (f32x4)0.f;
    f32x4* prow = reinterpret_cast<f32x4*>(prob + (size_t)row * PROB_LD);
    __builtin_nontemporal_store(z4, prow + lane);
    __builtin_nontemporal_store(z4, prow + 64 + lane);
  }

  // exact f32 rescore of the 12 candidates
  const float4* a4 = reinterpret_cast<const float4*>(img + (size_t)row * DIM);
  const float4 a0 = a4[lane], a1 = a4[64 + lane];
  float dv[KCAND];
#pragma unroll
  for (int j = 0; j < KCAND; ++j) {
    const float4* p4 = reinterpret_cast<const float4*>(proto + (size_t)ci[j] * DIM);
    const float4 b0 = p4[lane], b1 = p4[64 + lane];
    float s = 0.f;
    s = fmaf(a0.x, b0.x, s); s = fmaf(a0.y, b0.y, s);
    s = fmaf(a0.z, b0.z, s); s = fmaf(a0.w, b0.w, s);
    s = fmaf(a1.x, b1.x, s); s = fmaf(a1.y, b1.y, s);
    s = fmaf(a1.z, b1.z, s); s = fmaf(a1.w, b1.w, s);
#pragma unroll
    for (int off = 32; off; off >>= 1) s += __shfl_xor(s, off);
    dv[j] = s;
  }

  // top-10 pick (uniform across lanes) + bucket build (lane kk does pick kk)
  unsigned picked = 0;
  for (int kk = 0; kk < KSEL; ++kk) {
    float bv = -FLT_MAX;
    int   bj = 0;
#pragma unroll
    for (int j = 0; j < KCAND; ++j)
      if (!((picked >> j) & 1u) && dv[j] > bv) { bv = dv[j]; bj = j; }
    picked |= 1u << bj;
    if (lane == kk) {
      const int pp  = ci[bj];
      const int pos = atomicAdd(&counts[pp], 1);
      if (pos < CAP) buckets[pp * CAP + pos] = row;
    }
  }

  zero_share(zhi, ZS2, ZQ2, blockIdx.x * 256 + tid, 1024 * 256);
}

// ---------------------------------------------------------------------------
// Kernel 3: one block per proto; stage its 10 raw text rows in LDS + compute
// inverse norms (scale folded into the dot epilogue -- no rescale pass).
// Bucketed-row loop software-prefetches the next img row (L3-latency-bound).
// ---------------------------------------------------------------------------
__global__ __launch_bounds__(256) void k_compute(
    const float* __restrict__ img, const float* __restrict__ text,
    const int* __restrict__ counts, const int* __restrict__ buckets,
    const float* __restrict__ logit_scale, float* __restrict__ out)
{
  __shared__ float stext[KSEL * DIM];   // 20 KB (raw)
  __shared__ float sfac[KSEL];

  const int p    = blockIdx.x;
  const int tid  = threadIdx.x;
  const int wave = tid >> 6, lane = tid & 63;

  {
    const float4* src = reinterpret_cast<const float4*>(text + (size_t)p * KSEL * DIM);
    float4* dst = reinterpret_cast<float4*>(stext);
#pragma unroll
    for (int i = 0; i < 5; ++i) dst[tid + i * 256] = src[tid + i * 256];
  }
  __syncthreads();

  const float scale = expf(logit_scale[0]);
#pragma unroll
  for (int j = wave; j < KSEL; j += 4) {
    const float4* t4 = reinterpret_cast<const float4*>(stext + j * DIM);
    float4 v0 = t4[lane], v1 = t4[64 + lane];
    float s = 0.f;
    s = fmaf(v0.x, v0.x, s); s = fmaf(v0.y, v0.y, s);
    s = fmaf(v0.z, v0.z, s); s = fmaf(v0.w, v0.w, s);
    s = fmaf(v1.x, v1.x, s); s = fmaf(v1.y, v1.y, s);
    s = fmaf(v1.z, v1.z, s); s = fmaf(v1.w, v1.w, s);
#pragma unroll
    for (int off = 32; off; off >>= 1) s += __shfl_down(s, off);
    if (lane == 0) sfac[j] = scale / sqrtf(s);
  }
  __syncthreads();

  const int n = min(counts[p], CAP);
  const float4* st4 = reinterpret_cast<const float4*>(stext);
  const int* bkt = buckets + p * CAP;

  int row = -1, nrow;
  float4 a0, a1, na0, na1;
  if (wave < n) {
    row = bkt[wave];
    const float4* a4 = reinterpret_cast<const float4*>(img + (size_t)row * DIM);
    a0 = a4[lane]; a1 = a4[64 + lane];
  }

  for (int i = wave; i < n; i += 4) {
    // prefetch next row while computing this one
    const int inext = i + 4;
    if (inext < n) {
      nrow = bkt[inext];
      const float4* a4 = reinterpret_cast<const float4*>(img + (size_t)nrow * DIM);
      na0 = a4[lane]; na1 = a4[64 + lane];
    }

    float acc[KSEL];
#pragma unroll
    for (int j = 0; j < KSEL; ++j) {
      const float4 b0 = st4[j * 128 + lane];
      const float4 b1 = st4[j * 128 + 64 + lane];
      float s = 0.f;
      s = fmaf(a0.x, b0.x, s); s = fmaf(a0.y, b0.y, s);
      s = fmaf(a0.z, b0.z, s); s = fmaf(a0.w, b0.w, s);
      s = fmaf(a1.x, b1.x, s); s = fmaf(a1.y, b1.y, s);
      s = fmaf(a1.z, b1.z, s); s = fmaf(a1.w, b1.w, s);
      acc[j] = s;
    }
#pragma unroll
    for (int j = 0; j < KSEL; ++j) {
#pragma unroll
      for (int off = 32; off; off >>= 1)
        acc[j] += __shfl_xor(acc[j], off);
    }
    float v = acc[0];
#pragma unroll
    for (int j = 1; j < KSEL; ++j) if (lane == j) v = acc[j];
    if (lane < KSEL)
      out[(size_t)row * NCLASSES + p * KSEL + lane] = v * sfac[lane];

    row = nrow; a0 = na0; a1 = na1;
  }
}

// ---------------------------------------------------------------------------
extern "C" void kernel_launch(void* const* d_in, const int* in_sizes, int n_in,
                              void* d_out, int out_size, void* d_ws, size_t ws_size,
                              hipStream_t stream) {
  const float* img    = (const float*)d_in[0];
  const float* proto  = (const float*)d_in[1];
  const float* text   = (const float*)d_in[2];
  const float* lscale = (const float*)d_in[3];

  unsigned short* prob = (unsigned short*)d_out;
  f32x4*  zhi  = (f32x4*)((char*)d_out + PROB_BYTES);
  float*  out  = (float*)d_out;

  // ws layout (~1.03 MB)
  int* counts  = (int*)d_ws;                      // 1000*4 (pad to 4096)
  int* buckets = (int*)((char*)d_ws + 4096);      // 1000*256*4

  k_gemm<<<dim3(B_ROWS / GBM, 1024 / GBN), 256, 0, stream>>>(
      img, proto, prob, zhi, counts);
  k_select<<<B_ROWS / 4, 256, 0, stream>>>(prob, img, proto, counts, buckets, zhi);
  k_compute<<<NPROTO, 256, 0, stream>>>(img, text, counts, buckets, lscale, out);
}

// Round 10
// 99.413 us; speedup vs baseline: 6.1569x; 1.1152x over previous
//
#include <hip/hip_runtime.h>
#include <cfloat>
#include <math.h>

// Problem constants (fixed by the reference)
#define B_ROWS   4096
#define DIM      512
#define NPROTO   1000
#define NCLASSES 10000
#define KSEL     10
#define KCAND    12                // approx candidates rescored in f32
#define CAP      256               // bucket capacity (avg 41)
#define PROB_LD  1024

// d_out layout: prob f16 4096x1024 at [0, PROB_BYTES). k_select self-zeroes
// each prob row after consuming it; zhi = [PROB_BYTES, OUT) is zeroed in
// shares by k_gemm (post-loop) and k_select, always as POST-compute NT
// stores with no barrier after (R6 lesson: barrier forces vmcnt(0) drain).
#define PROB_BYTES 8388608u
#define OUT_BYTES  163840000u
#define ZHI_N4     ((OUT_BYTES - PROB_BYTES) / 16)   // 9715712 f32x4
#define ZQ1        6000000u                          // 96 MB zeroed by gemm
#define ZS1        0u
#define ZQ2        (ZHI_N4 - ZQ1)                    // ~59.5 MB by select
#define ZS2        ZQ1

// MFMA GEMM tiling
#define GBM 64
#define GBN 128
#define GBK 32
#define ALD 40                     // padded LDS row stride (bf16 elems)

typedef short s16x8 __attribute__((ext_vector_type(8)));
typedef float f32x4 __attribute__((ext_vector_type(4)));

static __device__ __forceinline__ unsigned short f2bf(float f) {
  unsigned int x = __float_as_uint(f);
  return (unsigned short)((x + 0x7fffu + ((x >> 16) & 1u)) >> 16);  // RNE
}
static __device__ __forceinline__ s16x8 cvt8(float4 a, float4 b) {
  s16x8 r;
  r[0]=f2bf(a.x); r[1]=f2bf(a.y); r[2]=f2bf(a.z); r[3]=f2bf(a.w);
  r[4]=f2bf(b.x); r[5]=f2bf(b.y); r[6]=f2bf(b.z); r[7]=f2bf(b.w);
  return r;
}
static __device__ __forceinline__ unsigned short f2h(float f) {
  _Float16 h = (_Float16)f;
  return __builtin_bit_cast(unsigned short, h);
}

// monotone map: IEEE f16 bits -> u16 preserving order (no NaNs here)
static __device__ __forceinline__ unsigned mono16(unsigned h) {
  return (h & 0x8000u) ? (~h & 0xffffu) : (h | 0x8000u);
}

static __device__ __forceinline__ void zero_share(
    f32x4* __restrict__ zhi, unsigned start, unsigned count,
    unsigned gth, unsigned nthreads)
{
  const f32x4 z4 = (f32x4)0.f;
  for (unsigned i = start + gth; i < start + count; i += nthreads)
    __builtin_nontemporal_store(z4, zhi + i);
}

// ---------------------------------------------------------------------------
// Kernel 1: prob(f16) = bf16(img) @ bf16(proto).T via 16x16x32 MFMA,
// f32->bf16 inline at the LDS-store site. Block (0,0) zeroes counts; every
// block writes its zhi zero share post-loop (async drain, no barrier after).
// ---------------------------------------------------------------------------
__global__ __launch_bounds__(256) void k_gemm(
    const float* __restrict__ img, const float* __restrict__ proto,
    unsigned short* __restrict__ prob, f32x4* __restrict__ zhi,
    int* __restrict__ counts)
{
  __shared__ short Al[GBM * ALD];   // 5 KB
  __shared__ short Bl[GBN * ALD];   // 10 KB

  const int tid  = threadIdx.x;
  const int lane = tid & 63, wave = tid >> 6;
  const int wr = wave >> 1, wc = wave & 1;
  const int row0 = blockIdx.x * GBM;
  const int col0 = blockIdx.y * GBN;
  const unsigned gth = (blockIdx.y * gridDim.x + blockIdx.x) * 256 + tid;

  const int sr = tid >> 2;          // staging row 0..63
  const int sc = (tid & 3) * 8;     // staging k-col 0,8,16,24

  int pa = col0 + sr;      if (pa > NPROTO - 1) pa = NPROTO - 1;
  int pb = col0 + 64 + sr; if (pb > NPROTO - 1) pb = NPROTO - 1;
  const float* gA  = img   + (size_t)(row0 + sr) * DIM + sc;
  const float* gB0 = proto + (size_t)pa * DIM + sc;
  const float* gB1 = proto + (size_t)pb * DIM + sc;

  float4 ra0  = *(const float4*)(gA);      float4 ra1  = *(const float4*)(gA + 4);
  float4 rb00 = *(const float4*)(gB0);     float4 rb01 = *(const float4*)(gB0 + 4);
  float4 rb10 = *(const float4*)(gB1);     float4 rb11 = *(const float4*)(gB1 + 4);

  f32x4 acc[2][4];
#pragma unroll
  for (int m = 0; m < 2; ++m)
#pragma unroll
    for (int n = 0; n < 4; ++n) acc[m][n] = (f32x4)0.f;

  const int kg = lane >> 4;   // k-group 0..3
  const int fr = lane & 15;   // fragment row/col

  for (int kt = 0; kt < DIM / GBK; ++kt) {
    *(s16x8*)&Al[sr * ALD + sc]        = cvt8(ra0, ra1);
    *(s16x8*)&Bl[sr * ALD + sc]        = cvt8(rb00, rb01);
    *(s16x8*)&Bl[(64 + sr) * ALD + sc] = cvt8(rb10, rb11);
    __syncthreads();

    if (kt + 1 < DIM / GBK) {
      const int k0 = (kt + 1) * GBK;
      ra0  = *(const float4*)(gA + k0);   ra1  = *(const float4*)(gA + k0 + 4);
      rb00 = *(const float4*)(gB0 + k0);  rb01 = *(const float4*)(gB0 + k0 + 4);
      rb10 = *(const float4*)(gB1 + k0);  rb11 = *(const float4*)(gB1 + k0 + 4);
    }

    s16x8 af[2], bf[4];
#pragma unroll
    for (int m = 0; m < 2; ++m)
      af[m] = *(const s16x8*)&Al[(wr * 32 + m * 16 + fr) * ALD + kg * 8];
#pragma unroll
    for (int n = 0; n < 4; ++n)
      bf[n] = *(const s16x8*)&Bl[(wc * 64 + n * 16 + fr) * ALD + kg * 8];
#pragma unroll
    for (int m = 0; m < 2; ++m)
#pragma unroll
      for (int n = 0; n < 4; ++n)
        acc[m][n] = __builtin_amdgcn_mfma_f32_16x16x32_bf16(
            af[m], bf[n], acc[m][n], 0, 0, 0);
    __syncthreads();
  }

  // epilogue: C/D layout (m89/m91): col = lane&15, row = (lane>>4)*4 + reg
#pragma unroll
  for (int m = 0; m < 2; ++m)
#pragma unroll
    for (int n = 0; n < 4; ++n) {
      const int r = row0 + wr * 32 + m * 16 + (lane >> 4) * 4;
      const int c = col0 + wc * 64 + n * 16 + fr;
#pragma unroll
      for (int reg = 0; reg < 4; ++reg)
        prob[(size_t)(r + reg) * PROB_LD + c] = f2h(acc[m][n][reg]);
    }

  if (blockIdx.x == 0 && blockIdx.y == 0)
    for (int i = tid; i < NPROTO; i += 256) counts[i] = 0;

  // post-loop zero share: no barrier after -> fully async drain
  zero_share(zhi, ZS1, ZQ1, gth, 512 * 256);
}

// ---------------------------------------------------------------------------
// Kernel 2: fused top-12 -> f32 rescore -> top-10 pick -> bucket build.
// One wave per row, NO LDS: candidates live in registers as packed u32
// (mono16(f16)<<16)|(0xffff-col) -- value-major, lowest-index tie-break,
// all entries distinct (index baked in) so clear-by-equality works.
// ---------------------------------------------------------------------------
__global__ __launch_bounds__(256) void k_select(
    unsigned short* __restrict__ prob, const float* __restrict__ img,
    const float* __restrict__ proto, int* __restrict__ counts,
    int* __restrict__ buckets, f32x4* __restrict__ zhi)
{
  const int tid  = threadIdx.x;
  const int wave = tid >> 6, lane = tid & 63;
  const int row  = blockIdx.x * 4 + wave;

  // lane l owns u32 words l*8 .. l*8+7 of the row = cols l*16 .. l*16+15
  unsigned cand[16];
  {
    const uint4* pu = reinterpret_cast<const uint4*>(
        prob + (size_t)row * PROB_LD) + lane * 2;
    const uint4 w0 = pu[0], w1 = pu[1];
    const unsigned w[8] = {w0.x, w0.y, w0.z, w0.w, w1.x, w1.y, w1.z, w1.w};
    const int cbase = lane * 16;
#pragma unroll
    for (int r = 0; r < 8; ++r) {
      const int c0 = cbase + r * 2;
      const unsigned lo = w[r] & 0xffffu, hi = w[r] >> 16;
      cand[r * 2]     = (c0     < NPROTO) ? ((mono16(lo) << 16) | (0xffffu - c0))       : 0u;
      cand[r * 2 + 1] = (c0 + 1 < NPROTO) ? ((mono16(hi) << 16) | (0xffffu - (c0 + 1))) : 0u;
    }
  }

  // 12 rounds of pure-VALU wave argmax
  int ci[KCAND];
#pragma unroll
  for (int kk = 0; kk < KCAND; ++kk) {
    unsigned best = cand[0];
#pragma unroll
    for (int r = 1; r < 16; ++r) best = max(best, cand[r]);
#pragma unroll
    for (int off = 32; off; off >>= 1)
      best = max(best, (unsigned)__shfl_xor((int)best, off));
    ci[kk] = 0xffff - (int)(best & 0xffffu);
#pragma unroll
    for (int r = 0; r < 16; ++r)
      if (cand[r] == best) cand[r] = 0u;
  }

  // self-zero the consumed f16 prob row (2 KB = 128 f32x4)
  {
    const f32x4 z4 = (f32x4)0.f;
    f32x4* prow = reinterpret_cast<f32x4*>(prob + (size_t)row * PROB_LD);
    __builtin_nontemporal_store(z4, prow + lane);
    __builtin_nontemporal_store(z4, prow + 64 + lane);
  }

  // exact f32 rescore of the 12 candidates
  const float4* a4 = reinterpret_cast<const float4*>(img + (size_t)row * DIM);
  const float4 a0 = a4[lane], a1 = a4[64 + lane];
  float dv[KCAND];
#pragma unroll
  for (int j = 0; j < KCAND; ++j) {
    const float4* p4 = reinterpret_cast<const float4*>(proto + (size_t)ci[j] * DIM);
    const float4 b0 = p4[lane], b1 = p4[64 + lane];
    float s = 0.f;
    s = fmaf(a0.x, b0.x, s); s = fmaf(a0.y, b0.y, s);
    s = fmaf(a0.z, b0.z, s); s = fmaf(a0.w, b0.w, s);
    s = fmaf(a1.x, b1.x, s); s = fmaf(a1.y, b1.y, s);
    s = fmaf(a1.z, b1.z, s); s = fmaf(a1.w, b1.w, s);
#pragma unroll
    for (int off = 32; off; off >>= 1) s += __shfl_xor(s, off);
    dv[j] = s;
  }

  // top-10 pick (uniform across lanes) + bucket build (lane kk does pick kk)
  unsigned picked = 0;
  for (int kk = 0; kk < KSEL; ++kk) {
    float bv = -FLT_MAX;
    int   bj = 0;
#pragma unroll
    for (int j = 0; j < KCAND; ++j)
      if (!((picked >> j) & 1u) && dv[j] > bv) { bv = dv[j]; bj = j; }
    picked |= 1u << bj;
    if (lane == kk) {
      const int pp  = ci[bj];
      const int pos = atomicAdd(&counts[pp], 1);
      if (pos < CAP) buckets[pp * CAP + pos] = row;
    }
  }

  zero_share(zhi, ZS2, ZQ2, blockIdx.x * 256 + tid, 1024 * 256);
}

// ---------------------------------------------------------------------------
// Kernel 3: one block per proto; stage its 10 raw text rows in LDS + compute
// inverse norms (scale folded into the dot epilogue -- no rescale pass).
// Bucketed-row loop software-prefetches the next img row (L3-latency-bound).
// ---------------------------------------------------------------------------
__global__ __launch_bounds__(256) void k_compute(
    const float* __restrict__ img, const float* __restrict__ text,
    const int* __restrict__ counts, const int* __restrict__ buckets,
    const float* __restrict__ logit_scale, float* __restrict__ out)
{
  __shared__ float stext[KSEL * DIM];   // 20 KB (raw)
  __shared__ float sfac[KSEL];

  const int p    = blockIdx.x;
  const int tid  = threadIdx.x;
  const int wave = tid >> 6, lane = tid & 63;

  {
    const float4* src = reinterpret_cast<const float4*>(text + (size_t)p * KSEL * DIM);
    float4* dst = reinterpret_cast<float4*>(stext);
#pragma unroll
    for (int i = 0; i < 5; ++i) dst[tid + i * 256] = src[tid + i * 256];
  }
  __syncthreads();

  const float scale = expf(logit_scale[0]);
#pragma unroll
  for (int j = wave; j < KSEL; j += 4) {
    const float4* t4 = reinterpret_cast<const float4*>(stext + j * DIM);
    float4 v0 = t4[lane], v1 = t4[64 + lane];
    float s = 0.f;
    s = fmaf(v0.x, v0.x, s); s = fmaf(v0.y, v0.y, s);
    s = fmaf(v0.z, v0.z, s); s = fmaf(v0.w, v0.w, s);
    s = fmaf(v1.x, v1.x, s); s = fmaf(v1.y, v1.y, s);
    s = fmaf(v1.z, v1.z, s); s = fmaf(v1.w, v1.w, s);
#pragma unroll
    for (int off = 32; off; off >>= 1) s += __shfl_down(s, off);
    if (lane == 0) sfac[j] = scale / sqrtf(s);
  }
  __syncthreads();

  const int n = min(counts[p], CAP);
  const float4* st4 = reinterpret_cast<const float4*>(stext);
  const int* bkt = buckets + p * CAP;

  int row = -1, nrow;
  float4 a0, a1, na0, na1;
  if (wave < n) {
    row = bkt[wave];
    const float4* a4 = reinterpret_cast<const float4*>(img + (size_t)row * DIM);
    a0 = a4[lane]; a1 = a4[64 + lane];
  }

  for (int i = wave; i < n; i += 4) {
    // prefetch next row while computing this one
    const int inext = i + 4;
    if (inext < n) {
      nrow = bkt[inext];
      const float4* a4 = reinterpret_cast<const float4*>(img + (size_t)nrow * DIM);
      na0 = a4[lane]; na1 = a4[64 + lane];
    }

    float acc[KSEL];
#pragma unroll
    for (int j = 0; j < KSEL; ++j) {
      const float4 b0 = st4[j * 128 + lane];
      const float4 b1 = st4[j * 128 + 64 + lane];
      float s = 0.f;
      s = fmaf(a0.x, b0.x, s); s = fmaf(a0.y, b0.y, s);
      s = fmaf(a0.z, b0.z, s); s = fmaf(a0.w, b0.w, s);
      s = fmaf(a1.x, b1.x, s); s = fmaf(a1.y, b1.y, s);
      s = fmaf(a1.z, b1.z, s); s = fmaf(a1.w, b1.w, s);
      acc[j] = s;
    }
#pragma unroll
    for (int j = 0; j < KSEL; ++j) {
#pragma unroll
      for (int off = 32; off; off >>= 1)
        acc[j] += __shfl_xor(acc[j], off);
    }
    float v = acc[0];
#pragma unroll
    for (int j = 1; j < KSEL; ++j) if (lane == j) v = acc[j];
    if (lane < KSEL)
      out[(size_t)row * NCLASSES + p * KSEL + lane] = v * sfac[lane];

    row = nrow; a0 = na0; a1 = na1;
  }
}

// ---------------------------------------------------------------------------
extern "C" void kernel_launch(void* const* d_in, const int* in_sizes, int n_in,
                              void* d_out, int out_size, void* d_ws, size_t ws_size,
                              hipStream_t stream) {
  const float* img    = (const float*)d_in[0];
  const float* proto  = (const float*)d_in[1];
  const float* text   = (const float*)d_in[2];
  const float* lscale = (const float*)d_in[3];

  unsigned short* prob = (unsigned short*)d_out;
  f32x4*  zhi  = (f32x4*)((char*)d_out + PROB_BYTES);
  float*  out  = (float*)d_out;

  // ws layout (~1.03 MB)
  int* counts  = (int*)d_ws;                      // 1000*4 (pad to 4096)
  int* buckets = (int*)((char*)d_ws + 4096);      // 1000*256*4

  k_gemm<<<dim3(B_ROWS / GBM, 1024 / GBN), 256, 0, stream>>>(
      img, proto, prob, zhi, counts);
  k_select<<<B_ROWS / 4, 256, 0, stream>>>(prob, img, proto, counts, buckets, zhi);
  k_compute<<<NPROTO, 256, 0, stream>>>(img, text, counts, buckets, lscale, out);
}